// Round 7
// baseline (3312.571 us; speedup 1.0000x reference)
//
#include <hip/hip_runtime.h>

#define B_ 64
#define T_ 256
#define LC_ 16
#define CV_ 128
#define CE_ 100
#define WE_ 300
#define CH_ 100
#define WH_ 300
#define NTAG 20
#define START_ 18
#define STOP_ 19
#define NEG_ -10000.0f
#define NSEQ (B_*T_)          // 16384
#define GW (4*WH_)            // 1200
#define KF (WE_+CH_)          // 400
#define NW_ 25                // workgroups per direction in k_word2
#define UH_ 12                // hidden units per workgroup (25*12=300)
#define SLOT_DW 9600          // 25*64*6 dwords per slot
#define DIR_DW (257*SLOT_DW)  // dwords per direction
#define FLAG_STRIDE 64        // dwords between flags (256 B)
#define FLAGS_DW (2*NW_*FLAG_STRIDE)  // 3200 dwords

typedef unsigned short ushort_t;
typedef unsigned long long ull_t;
typedef __attribute__((ext_vector_type(8))) short bf16x8;
typedef __attribute__((ext_vector_type(4))) float f32x4;
typedef __attribute__((ext_vector_type(4))) unsigned int u32x4;
union BF8 { bf16x8 v; ushort_t u[8]; };

__device__ inline float bf2f(ushort_t u){ return __uint_as_float(((unsigned int)u)<<16); }
__device__ inline ushort_t f2bf(float f){
  unsigned int x = __float_as_uint(f);
  unsigned int r = (x + 0x7fffu + ((x>>16)&1u)) >> 16;
  return (ushort_t)r;
}
__device__ inline float sigm(float x){ return 1.f/(1.f+__expf(-x)); }
__device__ inline float ftanh(float x){
  float ax = fabsf(x);
  float e = __expf(-2.f*ax);
  float t = (1.f-e)/(1.f+e);
  return copysignf(t, x);
}

// ---------- 0. init: zero h slot 0 (both dirs) + flags
__global__ __launch_bounds__(256) void k_init(unsigned int* __restrict__ hh, int* __restrict__ flags){
  int idx = blockIdx.x*256 + threadIdx.x;
  if (idx < SLOT_DW) hh[idx] = 0u;
  else if (idx < 2*SLOT_DW) hh[DIR_DW + (idx - SLOT_DW)] = 0u;
  else if (idx < 2*SLOT_DW + FLAGS_DW) flags[idx - 2*SLOT_DW] = 0;
}

// ---------- 1. char gate table: Ec[r][c] = char_emb[c] . cW_ih[r] + cb_ih[r]+cb_hh[r]
__global__ __launch_bounds__(256) void k_ctab(const float* __restrict__ cemb,
    const float* __restrict__ cWih, const float* __restrict__ cbih,
    const float* __restrict__ cbhh, float* __restrict__ Ec){
  int idx = blockIdx.x*256 + threadIdx.x;      // 51200 = 400*128
  int r = idx >> 7, c = idx & 127;
  float a = cbih[r] + cbhh[r];
  for (int k=0;k<CE_;++k) a += cemb[c*CE_+k]*cWih[r*CE_+k];
  Ec[r*128 + c] = a;
}

// ---------- 2. char LSTM: 64 seqs per WG, wave w owns units [25w,25w+25)
__global__ __launch_bounds__(256) void k_char(const float* __restrict__ Ec,
    const float* __restrict__ Whh, const int* __restrict__ char_x,
    float* __restrict__ c_h){
  __shared__ __attribute__((aligned(16))) float h_s[64][108];
  __shared__ __attribute__((aligned(16))) float c_s[64][108];
  int tid = threadIdx.x;
  int lane = tid & 63;
  int w = __builtin_amdgcn_readfirstlane(tid >> 6);
  int seq = blockIdx.x*64 + lane;
  float* hs = &h_s[0][0]; float* cs = &c_s[0][0];
  for (int i=tid; i<64*108; i+=256){ hs[i]=0.f; cs[i]=0.f; }
  __syncthreads();
  const int* cx = char_x + (size_t)seq*LC_;
  #pragma unroll 1
  for (int t=0; t<LC_; ++t){
    float hr[100];
    #pragma unroll
    for (int q=0;q<25;++q){
      float4 v = *(const float4*)&h_s[lane][q*4];
      hr[q*4]=v.x; hr[q*4+1]=v.y; hr[q*4+2]=v.z; hr[q*4+3]=v.w;
    }
    int ch = cx[t];
    __syncthreads();
    #pragma unroll 1
    for (int jj=0;jj<25;++jj){
      int j = w*25 + jj;
      float ai = Ec[(j       )*128 + ch];
      float af = Ec[(100 + j )*128 + ch];
      float ag = Ec[(200 + j )*128 + ch];
      float ao = Ec[(300 + j )*128 + ch];
      const float* wi = Whh + (size_t)(j      )*CE_;
      const float* wf = Whh + (size_t)(100 + j)*CE_;
      const float* wg = Whh + (size_t)(200 + j)*CE_;
      const float* wo = Whh + (size_t)(300 + j)*CE_;
      #pragma unroll
      for (int k=0;k<100;++k){
        float hk = hr[k];
        ai += wi[k]*hk; af += wf[k]*hk; ag += wg[k]*hk; ao += wo[k]*hk;
      }
      float I = sigm(ai), F = sigm(af), G = ftanh(ag), O = sigm(ao);
      float cn = F*c_s[lane][j] + I*G;
      float hn = O*ftanh(cn);
      if (ch > 0){ c_s[lane][j] = cn; h_s[lane][j] = hn; }
    }
    __syncthreads();
  }
  #pragma unroll 1
  for (int jj=0;jj<25;++jj){ int j=w*25+jj; c_h[(size_t)seq*CH_+j] = h_s[lane][j]; }
}

// ---------- 3. feat builder: feat[t][b][0..400) bf16 = concat(wemb[word_x], c_h)
__global__ __launch_bounds__(256) void k_feat(const int* __restrict__ word_x,
    const float* __restrict__ wemb, const float* __restrict__ c_h,
    ushort_t* __restrict__ feat){
  int gid = blockIdx.x*256 + threadIdx.x;      // 16384*100 groups of 4 cols
  int rf = gid / 100;                          // rf = t*64 + b
  int j4 = gid - rf*100;
  int k = 4*j4;
  int t = rf >> 6, b = rf & 63;
  int seq = b*T_ + t;
  float4 v;
  if (k < WE_){ int wid = word_x[seq]; v = *(const float4*)&wemb[(size_t)wid*WE_ + k]; }
  else        { v = *(const float4*)&c_h[(size_t)seq*CH_ + (k - WE_)]; }
  ushort4 u; u.x=f2bf(v.x); u.y=f2bf(v.y); u.z=f2bf(v.z); u.w=f2bf(v.w);
  *(ushort4*)&feat[(size_t)rf*KF + k] = u;
}

// ---------- 4. word LSTM: distributed recurrence, persistent weights in VGPRs,
//              MFMA gates, spread-flag handshake + coalesced device-scope publish.
__global__ __launch_bounds__(512, 2) void k_word2(
    const ushort_t* __restrict__ feat, unsigned int* __restrict__ hhd,
    const float* __restrict__ fWih, const float* __restrict__ fWhh,
    const float* __restrict__ fbih, const float* __restrict__ fbhh,
    const float* __restrict__ bWih, const float* __restrict__ bWhh,
    const float* __restrict__ bbih, const float* __restrict__ bbhh,
    const int* __restrict__ word_x, int* __restrict__ flags){
  extern __shared__ char smem[];
  ushort_t* h_s    = (ushort_t*)smem;                          // [64][328] bf16 = 41984 B
  ushort_t* f_s    = (ushort_t*)(smem + 64*328*2);             // [64][416] bf16 = 53248 B
  float*    g_s    = (float*)   (smem + 64*328*2 + 64*416*2);  // [64][52] f32   = 13312 B
  unsigned* mask_s = (unsigned*)(smem + 64*328*2 + 64*416*2 + 64*52*4); // [64][8] = 2048 B
  unsigned* pub    = (unsigned*)(smem + 64*328*2 + 64*416*2 + 64*52*4 + 2048); // [384] = 1536 B
  const int tid  = threadIdx.x;
  const int lane = tid & 63;
  const int w    = tid >> 6;         // 8 waves
  const int dir  = blockIdx.x & 1;
  const int g    = blockIdx.x >> 1;  // 0..24
  const int u0   = g * UH_;
  const int tm   = w & 3;            // m-tile (batch 16-row group)
  const int grp  = w >> 2;           // 0: n-tiles {0,1}; 1: n-tile {2}
  const bool two = (grp == 0);
  const int tnb  = grp ? 2 : 0;
  const float* Wih = dir ? bWih : fWih;
  const float* Whh = dir ? bWhh : fWhh;
  const float* bi  = dir ? bbih : fbih;
  const float* bh  = dir ? bbhh : fbhh;
  int* myflags = flags + dir*NW_*FLAG_STRIDE;

  // ---- persistent B fragments (W_ih: 13 k-slabs; W_hh: 10 k-slabs)
  bf16x8 B2[2][13], B1[2][10];
  {
    const int kb = 8*(lane >> 4);
    #pragma unroll
    for (int ti=0; ti<2; ++ti){
      if (ti == 0 || two){
        int nl = 16*(tnb+ti) + (lane & 15);
        int r  = (nl & 3)*WH_ + u0 + (nl >> 2);   // gate q*300 + unit
        #pragma unroll
        for (int kk=0; kk<13; ++kk){
          BF8 tmp;
          #pragma unroll
          for (int j=0; j<8; ++j){
            int k = 32*kk + kb + j;
            tmp.u[j] = (k < KF) ? f2bf(Wih[(size_t)r*KF + k]) : (ushort_t)0;
          }
          B2[ti][kk] = tmp.v;
        }
        #pragma unroll
        for (int kk=0; kk<10; ++kk){
          BF8 tmp;
          #pragma unroll
          for (int j=0; j<8; ++j){
            int k = 32*kk + kb + j;
            tmp.u[j] = (k < WH_) ? f2bf(Whh[(size_t)r*WH_ + k]) : (ushort_t)0;
          }
          B1[ti][kk] = tmp.v;
        }
      }
    }
  }
  unsigned* hdl = (unsigned*)h_s;
  // ---- zero LDS K-padding: h_s dword cols 150..163, f_s shorts 400..415
  for (int idx=tid; idx<64*14; idx+=512){ int m = idx/14; hdl[m*164 + 150 + (idx - m*14)] = 0u; }
  for (int idx=tid; idx<64*16; idx+=512){ f_s[(idx>>4)*416 + 400 + (idx & 15)] = 0; }
  // ---- build word-mask bitmap: mask_s[b][t>>5] bit (t&31)
  if (tid < 512){
    int row = tid >> 3, dw = tid & 7;
    const int* wp = word_x + row*T_ + dw*32;
    unsigned bits = 0u;
    #pragma unroll
    for (int j4=0; j4<8; ++j4){
      int4 v = *(const int4*)(wp + 4*j4);
      bits |= (v.x>0 ? 1u:0u) << (4*j4);
      bits |= (v.y>0 ? 1u:0u) << (4*j4+1);
      bits |= (v.z>0 ? 1u:0u) << (4*j4+2);
      bits |= (v.w>0 ? 1u:0u) << (4*j4+3);
    }
    mask_s[row*8 + dw] = bits;
  }

  // ---- update threads: tid<384: m_u = tid&63, up = tid>>6 (units u0+2up, u0+2up+1)
  const int m_u = tid & 63;
  const int up  = tid >> 6;          // 0..5 for update threads
  float4 bias_a = {0,0,0,0}, bias_b = {0,0,0,0};
  if (tid < 384){
    int u = u0 + 2*up;
    bias_a.x = bi[0*WH_+u] + bh[0*WH_+u];
    bias_a.y = bi[1*WH_+u] + bh[1*WH_+u];
    bias_a.z = bi[2*WH_+u] + bh[2*WH_+u];
    bias_a.w = bi[3*WH_+u] + bh[3*WH_+u];
    bias_b.x = bi[0*WH_+u+1] + bh[0*WH_+u+1];
    bias_b.y = bi[1*WH_+u+1] + bh[1*WH_+u+1];
    bias_b.z = bi[2*WH_+u+1] + bh[2*WH_+u+1];
    bias_b.w = bi[3*WH_+u+1] + bh[3*WH_+u+1];
  }
  float c_a=0.f, h_a=0.f, c_b=0.f, h_b=0.f;
  const int arow_f = (16*tm + (lane&15))*416 + 8*(lane>>4);
  const int arow_h = (16*tm + (lane&15))*328 + 8*(lane>>4);
  __syncthreads();

  #pragma unroll 1
  for (int s=0; s<T_; ++s){
    int t = dir ? (T_-1-s) : s;
    // -- stage feat(t) first: latency hides under the poll
    {
      const ushort_t* fsrc = feat + (size_t)t*64*KF;
      for (int idx=tid; idx<3200; idx+=512){
        int m = idx/50, j = idx - m*50;
        uint4 v = *(const uint4*)(fsrc + m*KF + 8*j);
        *(uint4*)(f_s + m*416 + 8*j) = v;
      }
    }
    // -- wait until all WGs of this dir published slot s (spread flags, no RMW)
    if (w == 0 && s > 0){
      bool act = lane < NW_;
      for (int it=0; it<2000000; ++it){
        int f = act ? __hip_atomic_load(myflags + lane*FLAG_STRIDE, __ATOMIC_RELAXED, __HIP_MEMORY_SCOPE_AGENT)
                    : 0x7fffffff;
        if (__all(f >= s)) break;
        __builtin_amdgcn_s_sleep(1);
      }
    }
    __syncthreads();
    // -- stage h(s): 4800 contiguous qwords, agent-scope loads, chunked layout
    {
      const ull_t* hsrc = (const ull_t*)(hhd + (size_t)(dir*257 + s)*SLOT_DW);
      ull_t v[10]; int di[10];
      #pragma unroll
      for (int i=0;i<10;++i){
        int idx = tid + 512*i;
        if (i < 9 || idx < 4800){
          int gc = idx / 192;
          int r  = idx - gc*192;
          int b  = r/3, q = r - b*3;
          di[i] = b*164 + gc*6 + 2*q;
          v[i] = __hip_atomic_load(hsrc + idx, __ATOMIC_RELAXED, __HIP_MEMORY_SCOPE_AGENT);
        }
      }
      #pragma unroll
      for (int i=0;i<10;++i){
        int idx = tid + 512*i;
        if (i < 9 || idx < 4800) *(ull_t*)(hdl + di[i]) = v[i];
      }
    }
    __syncthreads();
    // -- MFMA: gates(64 x 48-slice) = feat*Wih^T + h*Whh^T
    f32x4 acc0a = {0,0,0,0}, acc0b = {0,0,0,0}, acc1a = {0,0,0,0}, acc1b = {0,0,0,0};
    #pragma unroll
    for (int kk=0; kk<13; ++kk){
      bf16x8 a = *(const bf16x8*)(f_s + arow_f + 32*kk);
      if (kk & 1){
        acc0b = __builtin_amdgcn_mfma_f32_16x16x32_bf16(a, B2[0][kk], acc0b, 0,0,0);
        if (two) acc1b = __builtin_amdgcn_mfma_f32_16x16x32_bf16(a, B2[1][kk], acc1b, 0,0,0);
      } else {
        acc0a = __builtin_amdgcn_mfma_f32_16x16x32_bf16(a, B2[0][kk], acc0a, 0,0,0);
        if (two) acc1a = __builtin_amdgcn_mfma_f32_16x16x32_bf16(a, B2[1][kk], acc1a, 0,0,0);
      }
    }
    #pragma unroll
    for (int kk=0; kk<10; ++kk){
      bf16x8 a = *(const bf16x8*)(h_s + arow_h + 32*kk);
      if (kk & 1){
        acc0b = __builtin_amdgcn_mfma_f32_16x16x32_bf16(a, B1[0][kk], acc0b, 0,0,0);
        if (two) acc1b = __builtin_amdgcn_mfma_f32_16x16x32_bf16(a, B1[1][kk], acc1b, 0,0,0);
      } else {
        acc0a = __builtin_amdgcn_mfma_f32_16x16x32_bf16(a, B1[0][kk], acc0a, 0,0,0);
        if (two) acc1a = __builtin_amdgcn_mfma_f32_16x16x32_bf16(a, B1[1][kk], acc1a, 0,0,0);
      }
    }
    // -- write gate fragments to g_s
    {
      int nb = 16*tnb + (lane & 15);
      int mr = 16*tm + 4*(lane >> 4);
      f32x4 s0 = acc0a + acc0b;
      #pragma unroll
      for (int r4=0; r4<4; ++r4) g_s[(mr+r4)*52 + nb] = s0[r4];
      if (two){
        f32x4 s1 = acc1a + acc1b;
        #pragma unroll
        for (int r4=0; r4<4; ++r4) g_s[(mr+r4)*52 + nb + 16] = s1[r4];
      }
    }
    __syncthreads();
    // -- elementwise LSTM update -> pack into LDS pub buffer
    if (tid < 384){
      int mt = (mask_s[m_u*8 + (t>>5)] >> (t&31)) & 1u;
      float4 ga = *(const float4*)(g_s + m_u*52 + 8*up);
      float4 gb = *(const float4*)(g_s + m_u*52 + 8*up + 4);
      {
        float gi = sigm (ga.x + bias_a.x);
        float gf = sigm (ga.y + bias_a.y);
        float gg = ftanh(ga.z + bias_a.z);
        float go = sigm (ga.w + bias_a.w);
        float cn = gf*c_a + gi*gg;
        float hn = go*ftanh(cn);
        if (mt){ c_a = cn; h_a = hn; }
      }
      {
        float gi = sigm (gb.x + bias_b.x);
        float gf = sigm (gb.y + bias_b.y);
        float gg = ftanh(gb.z + bias_b.z);
        float go = sigm (gb.w + bias_b.w);
        float cn = gf*c_b + gi*gg;
        float hn = go*ftanh(cn);
        if (mt){ c_b = cn; h_b = hn; }
      }
      pub[m_u*6 + up] = (unsigned)f2bf(h_a) | ((unsigned)f2bf(h_b) << 16);
    }
    __syncthreads();
    // -- coalesced device-scope publish: 96 x dwordx4 (12 fully-dirty 128B lines)
    if (tid < 96){
      u32x4 val = *(const u32x4*)(pub + 4*tid);
      unsigned* dst = hhd + (size_t)(dir*257 + s + 1)*SLOT_DW + g*384 + 4*tid;
      asm volatile("global_store_dwordx4 %0, %1, off sc1" :: "v"(dst), "v"(val) : "memory");
    }
    asm volatile("s_waitcnt vmcnt(0)" ::: "memory");
    __syncthreads();   // all publish stores drained
    if (tid == 0)
      __hip_atomic_store(myflags + g*FLAG_STRIDE, s + 1, __ATOMIC_RELAXED, __HIP_MEMORY_SCOPE_AGENT);
  }
}

// ---------- 5. logits: logits[dir][seq][tag] = h_dir(t) . outW[tag][dir*300..]
__global__ __launch_bounds__(320) void k_logits(const unsigned int* __restrict__ hhd,
    const float* __restrict__ outW, float* __restrict__ logits){
  __shared__ __attribute__((aligned(16))) ushort_t h_l[16][304];
  __shared__ __attribute__((aligned(16))) float    w_l[20][304];
  int tid = threadIdx.x;
  int dir = blockIdx.y;
  for (int idx=tid; idx<20*304; idx+=320){
    int tag = idx/304, k = idx - tag*304;
    w_l[tag][k] = (k < WH_) ? outW[(size_t)tag*(2*WH_) + dir*WH_ + k] : 0.f;
  }
  unsigned* hld = (unsigned*)&h_l[0][0];
  for (int idx=tid; idx<2400; idx+=320){       // 16 rows x 150 dwords
    int m = idx/150, d = idx - m*150;
    int gc = d/6, q = d - gc*6;
    int seq = blockIdx.x*16 + m;
    int b = seq >> 8, t = seq & 255;
    int slot = dir ? (T_ - t) : (t + 1);
    hld[m*152 + d] = hhd[(size_t)(dir*257 + slot)*SLOT_DW + (gc*64 + b)*6 + q];
  }
  __syncthreads();
  int sq = tid/20, tag = tid - sq*20;
  float acc = 0.f;
  #pragma unroll
  for (int jj=0; jj<75; ++jj){
    ushort_t h0 = h_l[sq][4*jj+0], h1 = h_l[sq][4*jj+1];
    ushort_t h2 = h_l[sq][4*jj+2], h3 = h_l[sq][4*jj+3];
    float4 wv = *(const float4*)&w_l[tag][4*jj];
    acc += bf2f(h0)*wv.x + bf2f(h1)*wv.y + bf2f(h2)*wv.z + bf2f(h3)*wv.w;
  }
  int seq = blockIdx.x*16 + sq;
  logits[((size_t)dir*NSEQ + seq)*NTAG + tag] = acc;
}

// ---------- 6. CRF forward + gold score (one wave per batch element)
__global__ __launch_bounds__(64) void k_crf(const float* __restrict__ logits,
    const float* __restrict__ out_b, const float* __restrict__ tr,
    const int* __restrict__ word_x, const int* __restrict__ y,
    float* __restrict__ out){
  __shared__ float tr_s[NTAG][21];
  __shared__ float al[NTAG];
  __shared__ float tmp[NTAG];
  int b = blockIdx.x, lane = threadIdx.x;
  for (int idx=lane; idx<NTAG*NTAG; idx+=64) tr_s[idx/NTAG][idx%NTAG] = tr[idx];
  if (lane < NTAG) al[lane] = (lane == START_) ? 0.f : NEG_;
  __syncthreads();
  const float* lf = logits + (size_t)b*T_*NTAG;
  const float* lb = logits + (size_t)NSEQ*NTAG + (size_t)b*T_*NTAG;
  #pragma unroll 1
  for (int t=0; t<T_; ++t){
    float anew = 0.f;
    int m_t = word_x[b*T_ + t] > 0;
    if (lane < NTAG){
      float hv = lf[t*NTAG + lane] + lb[t*NTAG + lane] + out_b[lane];
      hv = fminf(fmaxf(hv, -1e6f), 1e6f);
      float mx = -3.4e38f;
      #pragma unroll
      for (int j=0;j<NTAG;++j) mx = fmaxf(mx, al[j] + tr_s[lane][j]);
      float ss = 0.f;
      #pragma unroll
      for (int j=0;j<NTAG;++j) ss += __expf(al[j] + tr_s[lane][j] - mx);
      anew = __logf(ss) + mx + hv;
      if (!m_t) anew = al[lane];
    }
    __syncthreads();
    if (lane < NTAG) al[lane] = anew;
    __syncthreads();
  }
  if (lane < NTAG) tmp[lane] = al[lane] + tr_s[STOP_][lane];
  __syncthreads();
  float sc = 0.f; int cnt = 0;
  #pragma unroll 1
  for (int q=0;q<4;++q){
    int t = lane + 64*q;
    if (word_x[b*T_ + t] > 0){
      int yt = y[b*T_ + t];
      int yp = (t == 0) ? START_ : y[b*T_ + t - 1];
      float ev = lf[t*NTAG + yt] + lb[t*NTAG + yt] + out_b[yt];
      ev = fminf(fmaxf(ev, -1e6f), 1e6f);
      sc += ev + tr_s[yt][yp];
      cnt++;
    }
  }
  for (int off=32; off; off>>=1){
    sc += __shfl_down(sc, off);
    cnt += __shfl_down(cnt, off);
  }
  if (lane == 0){
    float mx = -3.4e38f;
    for (int j=0;j<NTAG;++j) mx = fmaxf(mx, tmp[j]);
    float ss = 0.f;
    for (int j=0;j<NTAG;++j) ss += __expf(tmp[j] - mx);
    float Z = __logf(ss) + mx;
    int last = y[b*T_ + cnt - 1];
    sc += tr_s[STOP_][last];
    out[b] = Z - sc;
  }
}

extern "C" void kernel_launch(void* const* d_in, const int* in_sizes, int n_in,
                              void* d_out, int out_size, void* d_ws, size_t ws_size,
                              hipStream_t stream) {
  (void)in_sizes; (void)n_in; (void)out_size; (void)ws_size;
  const int*   word_x  = (const int*)  d_in[0];
  const int*   char_x  = (const int*)  d_in[1];
  const int*   y       = (const int*)  d_in[2];
  const float* wemb    = (const float*)d_in[3];
  const float* cemb    = (const float*)d_in[4];
  const float* cWih    = (const float*)d_in[5];
  const float* cWhh    = (const float*)d_in[6];
  const float* cbih    = (const float*)d_in[7];
  const float* cbhh    = (const float*)d_in[8];
  const float* fWih    = (const float*)d_in[9];
  const float* fWhh    = (const float*)d_in[10];
  const float* fbih    = (const float*)d_in[11];
  const float* fbhh    = (const float*)d_in[12];
  const float* bWih    = (const float*)d_in[13];
  const float* bWhh    = (const float*)d_in[14];
  const float* bbih    = (const float*)d_in[15];
  const float* bbhh    = (const float*)d_in[16];
  const float* outW    = (const float*)d_in[17];
  const float* outb    = (const float*)d_in[18];
  const float* trans   = (const float*)d_in[19];
  float* out = (float*)d_out;

  char* ws = (char*)d_ws;
  // layout (bytes, 256-aligned):
  float*        Ec     = (float*)       (ws + 0);          //   204,800
  float*        c_h    = (float*)       (ws + 204800);     // 6,553,600
  ushort_t*     feat   = (ushort_t*)    (ws + 6758400);    // 13,107,200
  unsigned int* hh     = (unsigned int*)(ws + 19865600);   // 2*257*9600*4 = 19,737,600
  int*          flags  = (int*)         (ws + 39603200);   // 3200 dwords = 12,800
  float*        logits = (float*)       (ws + 39616000);   // 2,621,440 -> end 42,237,440
  static const int LDS_W = 64*328*2 + 64*416*2 + 64*52*4 + 64*8*4 + 384*4;   // 112,128 B
  hipFuncSetAttribute((const void*)k_word2, hipFuncAttributeMaxDynamicSharedMemorySize, LDS_W);

  hipLaunchKernelGGL(k_init, dim3((2*SLOT_DW + FLAGS_DW + 255)/256), dim3(256), 0, stream, hh, flags);
  hipLaunchKernelGGL(k_ctab, dim3(200), dim3(256), 0, stream, cemb, cWih, cbih, cbhh, Ec);
  hipLaunchKernelGGL(k_char, dim3(256), dim3(256), 0, stream, Ec, cWhh, char_x, c_h);
  hipLaunchKernelGGL(k_feat, dim3(6400), dim3(256), 0, stream, word_x, wemb, c_h, feat);
  hipLaunchKernelGGL(k_word2, dim3(2*NW_), dim3(512), LDS_W, stream,
                     feat, hh, fWih, fWhh, fbih, fbhh, bWih, bWhh, bbih, bbhh, word_x, flags);
  hipLaunchKernelGGL(k_logits, dim3(NSEQ/16, 2), dim3(320), 0, stream, hh, outW, logits);
  hipLaunchKernelGGL(k_crf, dim3(64), dim3(64), 0, stream, logits, outb, trans, word_x, y, out);
}

// Round 8
// 3201.461 us; speedup vs baseline: 1.0347x; 1.0347x over previous
//
#include <hip/hip_runtime.h>

#define B_ 64
#define T_ 256
#define LC_ 16
#define CV_ 128
#define CE_ 100
#define WE_ 300
#define CH_ 100
#define WH_ 300
#define NTAG 20
#define START_ 18
#define STOP_ 19
#define NEG_ -10000.0f
#define NSEQ (B_*T_)          // 16384
#define GW (4*WH_)            // 1200
#define KF (WE_+CH_)          // 400
#define NW_ 25                // workgroups per direction in k_word2
#define UH_ 12                // hidden units per workgroup (25*12=300)
#define SLOT_DW 9600          // 25*64*6 dwords per slot
#define DIR_DW (257*SLOT_DW)  // 2,467,200 dwords per direction
#define SENT 0x7FC07FC0u      // bf16 NaN|NaN — never produced by finite h

typedef unsigned short ushort_t;
typedef unsigned long long ull_t;
typedef __attribute__((ext_vector_type(8))) short bf16x8;
typedef __attribute__((ext_vector_type(4))) float f32x4;
typedef __attribute__((ext_vector_type(4))) unsigned int u32x4;
union BF8 { bf16x8 v; ushort_t u[8]; };

__device__ inline float bf2f(ushort_t u){ return __uint_as_float(((unsigned int)u)<<16); }
__device__ inline ushort_t f2bf(float f){
  unsigned int x = __float_as_uint(f);
  unsigned int r = (x + 0x7fffu + ((x>>16)&1u)) >> 16;
  return (ushort_t)r;
}
__device__ inline float sigm(float x){ return 1.f/(1.f+__expf(-x)); }
__device__ inline float ftanh(float x){
  float ax = fabsf(x);
  float e = __expf(-2.f*ax);
  float t = (1.f-e)/(1.f+e);
  return copysignf(t, x);
}

// ---------- 0. init: slot 0 of each dir = 0, all other slots = sentinel
__global__ __launch_bounds__(256) void k_init(u32x4* __restrict__ hh4){
  size_t i = (size_t)blockIdx.x*256 + threadIdx.x;   // uint4 index
  size_t tot = (size_t)2*DIR_DW/4;
  if (i >= tot) return;
  size_t dw = i*4;
  unsigned sidx = (unsigned)((dw % DIR_DW) / SLOT_DW);
  unsigned val = (sidx == 0) ? 0u : SENT;
  u32x4 v = {val, val, val, val};
  hh4[i] = v;
}

// ---------- 1. transposed char gate table: Ec_t[c][r] = char_emb[c].cW_ih[r] + cb_ih[r]+cb_hh[r]
__global__ __launch_bounds__(256) void k_ctab(const float* __restrict__ cemb,
    const float* __restrict__ cWih, const float* __restrict__ cbih,
    const float* __restrict__ cbhh, float* __restrict__ Ec_t){
  int idx = blockIdx.x*256 + threadIdx.x;      // 51200 = 400*128
  int r = idx >> 7, c = idx & 127;
  float a = cbih[r] + cbhh[r];
  for (int k=0;k<CE_;++k) a += cemb[c*CE_+k]*cWih[r*CE_+k];
  Ec_t[c*400 + r] = a;
}

// ---------- 2. char LSTM (MFMA): 64 seqs/WG, 4 waves; Whh frags in VGPRs
__global__ __launch_bounds__(256) void k_char(const float* __restrict__ Ec_t,
    const float* __restrict__ Whh, const int* __restrict__ char_x,
    float* __restrict__ c_h){
  extern __shared__ char csm[];
  ushort_t* h_lds = (ushort_t*)csm;              // [64][132] bf16 = 16,896 B
  float*    g_lds = (float*)(csm + 64*132*2);    // [64][401] f32  = 102,656 B
  const int tid  = threadIdx.x;
  const int lane = tid & 63;
  const int w    = tid >> 6;                     // 4 waves
  const int tb   = w*6;                          // n-tile base (w3 also does tile 24)
  // ---- persistent B fragments: gates[r] x k(100->128)
  bf16x8 Bf[7][4];
  {
    int ntile = (w==3) ? 7 : 6;
    for (int tt=0; tt<ntile; ++tt){
      int r = (tb+tt)*16 + (lane & 15);
      #pragma unroll
      for (int ks=0; ks<4; ++ks){
        BF8 tmp;
        #pragma unroll
        for (int j=0; j<8; ++j){
          int k = 32*ks + 8*(lane>>4) + j;
          tmp.u[j] = (k < CH_) ? f2bf(Whh[(size_t)r*CH_ + k]) : (ushort_t)0;
        }
        Bf[tt][ks] = tmp.v;
      }
    }
  }
  for (int i=tid; i<64*132; i+=256) h_lds[i] = 0;
  // ---- update-thread state: seq = tid&63, units [25*(tid>>6), +25)
  const int seq_l = tid & 63;
  const int us    = tid >> 6;
  const int seqg  = blockIdx.x*64 + seq_l;
  const int u0    = us*25;
  float c_r[25], h_r[25];
  #pragma unroll
  for (int j=0;j<25;++j){ c_r[j]=0.f; h_r[j]=0.f; }
  const int* cx = char_x + (size_t)seqg*LC_;
  __syncthreads();
  #pragma unroll 1
  for (int t=0; t<LC_; ++t){
    // -- MFMA: g = h . Whh^T  (64 x 400)
    #pragma unroll
    for (int m=0; m<4; ++m){
      int abase = (16*m + (lane&15))*132 + 8*(lane>>4);
      bf16x8 a0 = *(const bf16x8*)(h_lds + abase);
      bf16x8 a1 = *(const bf16x8*)(h_lds + abase + 32);
      bf16x8 a2 = *(const bf16x8*)(h_lds + abase + 64);
      bf16x8 a3 = *(const bf16x8*)(h_lds + abase + 96);
      int rw = 16*m + 4*(lane>>4);
      #pragma unroll
      for (int tt=0; tt<6; ++tt){
        f32x4 acc = {0,0,0,0};
        acc = __builtin_amdgcn_mfma_f32_16x16x32_bf16(a0, Bf[tt][0], acc, 0,0,0);
        acc = __builtin_amdgcn_mfma_f32_16x16x32_bf16(a1, Bf[tt][1], acc, 0,0,0);
        acc = __builtin_amdgcn_mfma_f32_16x16x32_bf16(a2, Bf[tt][2], acc, 0,0,0);
        acc = __builtin_amdgcn_mfma_f32_16x16x32_bf16(a3, Bf[tt][3], acc, 0,0,0);
        int col = (tb+tt)*16 + (lane&15);
        #pragma unroll
        for (int r4=0;r4<4;++r4) g_lds[(rw+r4)*401 + col] = acc[r4];
      }
      if (w == 3){
        f32x4 acc = {0,0,0,0};
        acc = __builtin_amdgcn_mfma_f32_16x16x32_bf16(a0, Bf[6][0], acc, 0,0,0);
        acc = __builtin_amdgcn_mfma_f32_16x16x32_bf16(a1, Bf[6][1], acc, 0,0,0);
        acc = __builtin_amdgcn_mfma_f32_16x16x32_bf16(a2, Bf[6][2], acc, 0,0,0);
        acc = __builtin_amdgcn_mfma_f32_16x16x32_bf16(a3, Bf[6][3], acc, 0,0,0);
        int col = 24*16 + (lane&15);
        #pragma unroll
        for (int r4=0;r4<4;++r4) g_lds[(rw+r4)*401 + col] = acc[r4];
      }
    }
    int ch = cx[t];
    __syncthreads();
    // -- update: gates + Ec_t gather, c/h in regs, h -> LDS bf16
    {
      const float* ec = Ec_t + (size_t)ch*400;
      const float* gr = g_lds + seq_l*401;
      #pragma unroll
      for (int j=0;j<25;++j){
        int u = u0 + j;
        float gi = gr[u        ] + ec[u        ];
        float gf = gr[100 + u  ] + ec[100 + u  ];
        float gg = gr[200 + u  ] + ec[200 + u  ];
        float go = gr[300 + u  ] + ec[300 + u  ];
        float I = sigm(gi), F = sigm(gf), G = ftanh(gg), O = sigm(go);
        float cn = F*c_r[j] + I*G;
        float hn = O*ftanh(cn);
        if (ch > 0){ c_r[j] = cn; h_r[j] = hn; }
        h_lds[seq_l*132 + u] = f2bf(h_r[j]);
      }
    }
    __syncthreads();
  }
  #pragma unroll
  for (int j=0;j<25;++j) c_h[(size_t)seqg*CH_ + u0 + j] = h_r[j];
}

// ---------- 3. feat builder: feat[t][b][0..400) bf16 = concat(wemb[word_x], c_h)
__global__ __launch_bounds__(256) void k_feat(const int* __restrict__ word_x,
    const float* __restrict__ wemb, const float* __restrict__ c_h,
    ushort_t* __restrict__ feat){
  int gid = blockIdx.x*256 + threadIdx.x;      // 16384*100 groups of 4 cols
  int rf = gid / 100;                          // rf = t*64 + b
  int j4 = gid - rf*100;
  int k = 4*j4;
  int t = rf >> 6, b = rf & 63;
  int seq = b*T_ + t;
  float4 v;
  if (k < WE_){ int wid = word_x[seq]; v = *(const float4*)&wemb[(size_t)wid*WE_ + k]; }
  else        { v = *(const float4*)&c_h[(size_t)seq*CH_ + (k - WE_)]; }
  ushort4 u; u.x=f2bf(v.x); u.y=f2bf(v.y); u.z=f2bf(v.z); u.w=f2bf(v.w);
  *(ushort4*)&feat[(size_t)rf*KF + k] = u;
}

// ---------- 4. word LSTM: distributed recurrence, sentinel-poll handshake
//              (no flags, no fences, no producer drain)
__global__ __launch_bounds__(512, 2) void k_word2(
    const ushort_t* __restrict__ feat, unsigned int* __restrict__ hhd,
    const float* __restrict__ fWih, const float* __restrict__ fWhh,
    const float* __restrict__ fbih, const float* __restrict__ fbhh,
    const float* __restrict__ bWih, const float* __restrict__ bWhh,
    const float* __restrict__ bbih, const float* __restrict__ bbhh,
    const int* __restrict__ word_x){
  extern __shared__ char smem[];
  ushort_t* h_s    = (ushort_t*)smem;                          // [64][332] bf16 = 42,496 B
  ushort_t* f_s    = (ushort_t*)(smem + 64*332*2);             // [64][420] bf16 = 53,760 B
  float*    g_s    = (float*)   (smem + 64*332*2 + 64*420*2);  // [64][53] f32   = 13,568 B
  unsigned* mask_s = (unsigned*)(smem + 64*332*2 + 64*420*2 + 64*53*4); // 2048 B
  unsigned* pub    = (unsigned*)(smem + 64*332*2 + 64*420*2 + 64*53*4 + 2048); // 1536 B
  const int tid  = threadIdx.x;
  const int lane = tid & 63;
  const int w    = tid >> 6;         // 8 waves
  const int dir  = blockIdx.x & 1;
  const int g    = blockIdx.x >> 1;  // 0..24
  const int u0   = g * UH_;
  const int tm   = w & 3;            // m-tile (batch 16-row group)
  const int grp  = w >> 2;           // 0: n-tiles {0,1}; 1: n-tile {2}
  const bool two = (grp == 0);
  const int tnb  = grp ? 2 : 0;
  const float* Wih = dir ? bWih : fWih;
  const float* Whh = dir ? bWhh : fWhh;
  const float* bi  = dir ? bbih : fbih;
  const float* bh  = dir ? bbhh : fbhh;

  // ---- persistent B fragments (W_ih: 13 k-slabs; W_hh: 10 k-slabs)
  bf16x8 B2[2][13], B1[2][10];
  {
    const int kb = 8*(lane >> 4);
    #pragma unroll
    for (int ti=0; ti<2; ++ti){
      if (ti == 0 || two){
        int nl = 16*(tnb+ti) + (lane & 15);
        int r  = (nl & 3)*WH_ + u0 + (nl >> 2);   // gate q*300 + unit
        #pragma unroll
        for (int kk=0; kk<13; ++kk){
          BF8 tmp;
          #pragma unroll
          for (int j=0; j<8; ++j){
            int k = 32*kk + kb + j;
            tmp.u[j] = (k < KF) ? f2bf(Wih[(size_t)r*KF + k]) : (ushort_t)0;
          }
          B2[ti][kk] = tmp.v;
        }
        #pragma unroll
        for (int kk=0; kk<10; ++kk){
          BF8 tmp;
          #pragma unroll
          for (int j=0; j<8; ++j){
            int k = 32*kk + kb + j;
            tmp.u[j] = (k < WH_) ? f2bf(Whh[(size_t)r*WH_ + k]) : (ushort_t)0;
          }
          B1[ti][kk] = tmp.v;
        }
      }
    }
  }
  unsigned* hdl = (unsigned*)h_s;
  // ---- zero LDS K-padding: h_s dword cols 150..165, f_s shorts 400..419
  for (int idx=tid; idx<64*16; idx+=512){ int m = idx/16; hdl[m*166 + 150 + (idx - m*16)] = 0u; }
  for (int idx=tid; idx<64*20; idx+=512){ int m = idx/20; f_s[m*420 + 400 + (idx - m*20)] = 0; }
  // ---- build word-mask bitmap: mask_s[b][t>>5] bit (t&31)
  if (tid < 512){
    int row = tid >> 3, dw = tid & 7;
    const int* wp = word_x + row*T_ + dw*32;
    unsigned bits = 0u;
    #pragma unroll
    for (int j4=0; j4<8; ++j4){
      int4 v = *(const int4*)(wp + 4*j4);
      bits |= (v.x>0 ? 1u:0u) << (4*j4);
      bits |= (v.y>0 ? 1u:0u) << (4*j4+1);
      bits |= (v.z>0 ? 1u:0u) << (4*j4+2);
      bits |= (v.w>0 ? 1u:0u) << (4*j4+3);
    }
    mask_s[row*8 + dw] = bits;
  }

  // ---- update threads: tid<384: m_u = tid&63, up = tid>>6 (units u0+2up, u0+2up+1)
  const int m_u = tid & 63;
  const int up  = tid >> 6;          // 0..5 for update threads
  float4 bias_a = {0,0,0,0}, bias_b = {0,0,0,0};
  if (tid < 384){
    int u = u0 + 2*up;
    bias_a.x = bi[0*WH_+u] + bh[0*WH_+u];
    bias_a.y = bi[1*WH_+u] + bh[1*WH_+u];
    bias_a.z = bi[2*WH_+u] + bh[2*WH_+u];
    bias_a.w = bi[3*WH_+u] + bh[3*WH_+u];
    bias_b.x = bi[0*WH_+u+1] + bh[0*WH_+u+1];
    bias_b.y = bi[1*WH_+u+1] + bh[1*WH_+u+1];
    bias_b.z = bi[2*WH_+u+1] + bh[2*WH_+u+1];
    bias_b.w = bi[3*WH_+u+1] + bh[3*WH_+u+1];
  }
  float c_a=0.f, h_a=0.f, c_b=0.f, h_b=0.f;
  const int arow_f = (16*tm + (lane&15))*420 + 8*(lane>>4);
  const int arow_h = (16*tm + (lane&15))*332 + 8*(lane>>4);
  __syncthreads();

  #pragma unroll 1
  for (int s=0; s<T_; ++s){
    int t = dir ? (T_-1-s) : s;
    // -- stage feat(t): latency hides under the data poll below
    {
      const ushort_t* fsrc = feat + (size_t)t*64*KF;
      for (int idx=tid; idx<3200; idx+=512){
        int m = idx/50, j = idx - m*50;
        uint4 v = *(const uint4*)(fsrc + m*KF + 8*j);
        *(uint4*)(f_s + m*420 + 8*j) = v;
      }
    }
    // -- stage h(s): poll own data words until non-sentinel (no flags)
    {
      const ull_t* hsrc = (const ull_t*)(hhd + (size_t)(dir*257 + s)*SLOT_DW);
      ull_t v[10]; int di[10];
      unsigned pend = 0;
      #pragma unroll
      for (int i=0;i<10;++i){
        int idx = tid + 512*i;
        if (i < 9 || idx < 4800){
          int gc = idx/192, r = idx - gc*192;
          int b = r/3, q = r - b*3;
          di[i] = b*166 + gc*6 + 2*q;
          v[i] = __hip_atomic_load(hsrc + idx, __ATOMIC_RELAXED, __HIP_MEMORY_SCOPE_AGENT);
          if ((unsigned)v[i] == SENT || (unsigned)(v[i]>>32) == SENT) pend |= 1u<<i;
        }
      }
      for (int it=0; it<(1<<22) && pend; ++it){
        #pragma unroll
        for (int i=0;i<10;++i){
          if (pend & (1u<<i)){
            int idx = tid + 512*i;
            v[i] = __hip_atomic_load(hsrc + idx, __ATOMIC_RELAXED, __HIP_MEMORY_SCOPE_AGENT);
            if (!((unsigned)v[i] == SENT || (unsigned)(v[i]>>32) == SENT)) pend &= ~(1u<<i);
          }
        }
      }
      #pragma unroll
      for (int i=0;i<10;++i){
        int idx = tid + 512*i;
        if (i < 9 || idx < 4800) *(ull_t*)(hdl + di[i]) = v[i];
      }
    }
    __syncthreads();
    // -- MFMA: gates(64 x 48-slice) = feat*Wih^T + h*Whh^T
    f32x4 acc0a = {0,0,0,0}, acc0b = {0,0,0,0}, acc1a = {0,0,0,0}, acc1b = {0,0,0,0};
    #pragma unroll
    for (int kk=0; kk<13; ++kk){
      bf16x8 a = *(const bf16x8*)(f_s + arow_f + 32*kk);
      if (kk & 1){
        acc0b = __builtin_amdgcn_mfma_f32_16x16x32_bf16(a, B2[0][kk], acc0b, 0,0,0);
        if (two) acc1b = __builtin_amdgcn_mfma_f32_16x16x32_bf16(a, B2[1][kk], acc1b, 0,0,0);
      } else {
        acc0a = __builtin_amdgcn_mfma_f32_16x16x32_bf16(a, B2[0][kk], acc0a, 0,0,0);
        if (two) acc1a = __builtin_amdgcn_mfma_f32_16x16x32_bf16(a, B2[1][kk], acc1a, 0,0,0);
      }
    }
    #pragma unroll
    for (int kk=0; kk<10; ++kk){
      bf16x8 a = *(const bf16x8*)(h_s + arow_h + 32*kk);
      if (kk & 1){
        acc0b = __builtin_amdgcn_mfma_f32_16x16x32_bf16(a, B1[0][kk], acc0b, 0,0,0);
        if (two) acc1b = __builtin_amdgcn_mfma_f32_16x16x32_bf16(a, B1[1][kk], acc1b, 0,0,0);
      } else {
        acc0a = __builtin_amdgcn_mfma_f32_16x16x32_bf16(a, B1[0][kk], acc0a, 0,0,0);
        if (two) acc1a = __builtin_amdgcn_mfma_f32_16x16x32_bf16(a, B1[1][kk], acc1a, 0,0,0);
      }
    }
    // -- write gate fragments to g_s
    {
      int nb = 16*tnb + (lane & 15);
      int mr = 16*tm + 4*(lane >> 4);
      f32x4 s0 = acc0a + acc0b;
      #pragma unroll
      for (int r4=0; r4<4; ++r4) g_s[(mr+r4)*53 + nb] = s0[r4];
      if (two){
        f32x4 s1 = acc1a + acc1b;
        #pragma unroll
        for (int r4=0; r4<4; ++r4) g_s[(mr+r4)*53 + nb + 16] = s1[r4];
      }
    }
    __syncthreads();
    // -- elementwise LSTM update -> pack into LDS pub buffer
    if (tid < 384){
      int mt = (mask_s[m_u*8 + (t>>5)] >> (t&31)) & 1u;
      const float* gr = g_s + m_u*53 + 8*up;
      float ga0 = gr[0], ga1 = gr[1], ga2 = gr[2], ga3 = gr[3];
      float gb0 = gr[4], gb1 = gr[5], gb2 = gr[6], gb3 = gr[7];
      {
        float gi = sigm (ga0 + bias_a.x);
        float gf = sigm (ga1 + bias_a.y);
        float gg = ftanh(ga2 + bias_a.z);
        float go = sigm (ga3 + bias_a.w);
        float cn = gf*c_a + gi*gg;
        float hn = go*ftanh(cn);
        if (mt){ c_a = cn; h_a = hn; }
      }
      {
        float gi = sigm (gb0 + bias_b.x);
        float gf = sigm (gb1 + bias_b.y);
        float gg = ftanh(gb2 + bias_b.z);
        float go = sigm (gb3 + bias_b.w);
        float cn = gf*c_b + gi*gg;
        float hn = go*ftanh(cn);
        if (mt){ c_b = cn; h_b = hn; }
      }
      pub[m_u*6 + up] = (unsigned)f2bf(h_a) | ((unsigned)f2bf(h_b) << 16);
    }
    __syncthreads();
    // -- coalesced device-scope publish: fire-and-forget (consumers poll data)
    if (tid < 96){
      u32x4 val = *(const u32x4*)(pub + 4*tid);
      unsigned* dst = hhd + (size_t)(dir*257 + s + 1)*SLOT_DW + g*384 + 4*tid;
      asm volatile("global_store_dwordx4 %0, %1, off sc1" :: "v"(dst), "v"(val) : "memory");
    }
  }
}

// ---------- 5. logits: logits[dir][seq][tag] = h_dir(t) . outW[tag][dir*300..]
__global__ __launch_bounds__(320) void k_logits(const unsigned int* __restrict__ hhd,
    const float* __restrict__ outW, float* __restrict__ logits){
  __shared__ __attribute__((aligned(16))) ushort_t h_l[16][304];
  __shared__ __attribute__((aligned(16))) float    w_l[20][304];
  int tid = threadIdx.x;
  int dir = blockIdx.y;
  for (int idx=tid; idx<20*304; idx+=320){
    int tag = idx/304, k = idx - tag*304;
    w_l[tag][k] = (k < WH_) ? outW[(size_t)tag*(2*WH_) + dir*WH_ + k] : 0.f;
  }
  unsigned* hld = (unsigned*)&h_l[0][0];
  for (int idx=tid; idx<2400; idx+=320){       // 16 rows x 150 dwords
    int m = idx/150, d = idx - m*150;
    int gc = d/6, q = d - gc*6;
    int seq = blockIdx.x*16 + m;
    int b = seq >> 8, t = seq & 255;
    int slot = dir ? (T_ - t) : (t + 1);
    hld[m*152 + d] = hhd[(size_t)(dir*257 + slot)*SLOT_DW + (gc*64 + b)*6 + q];
  }
  __syncthreads();
  int sq = tid/20, tag = tid - sq*20;
  float acc = 0.f;
  #pragma unroll
  for (int jj=0; jj<75; ++jj){
    ushort_t h0 = h_l[sq][4*jj+0], h1 = h_l[sq][4*jj+1];
    ushort_t h2 = h_l[sq][4*jj+2], h3 = h_l[sq][4*jj+3];
    float4 wv = *(const float4*)&w_l[tag][4*jj];
    acc += bf2f(h0)*wv.x + bf2f(h1)*wv.y + bf2f(h2)*wv.z + bf2f(h3)*wv.w;
  }
  int seq = blockIdx.x*16 + sq;
  logits[((size_t)dir*NSEQ + seq)*NTAG + tag] = acc;
}

// ---------- 6. CRF forward + gold score (one wave per batch element)
__global__ __launch_bounds__(64) void k_crf(const float* __restrict__ logits,
    const float* __restrict__ out_b, const float* __restrict__ tr,
    const int* __restrict__ word_x, const int* __restrict__ y,
    float* __restrict__ out){
  __shared__ float tr_s[NTAG][21];
  __shared__ float al[NTAG];
  __shared__ float tmp[NTAG];
  int b = blockIdx.x, lane = threadIdx.x;
  for (int idx=lane; idx<NTAG*NTAG; idx+=64) tr_s[idx/NTAG][idx%NTAG] = tr[idx];
  if (lane < NTAG) al[lane] = (lane == START_) ? 0.f : NEG_;
  __syncthreads();
  const float* lf = logits + (size_t)b*T_*NTAG;
  const float* lb = logits + (size_t)NSEQ*NTAG + (size_t)b*T_*NTAG;
  #pragma unroll 1
  for (int t=0; t<T_; ++t){
    float anew = 0.f;
    int m_t = word_x[b*T_ + t] > 0;
    if (lane < NTAG){
      float hv = lf[t*NTAG + lane] + lb[t*NTAG + lane] + out_b[lane];
      hv = fminf(fmaxf(hv, -1e6f), 1e6f);
      float mx = -3.4e38f;
      #pragma unroll
      for (int j=0;j<NTAG;++j) mx = fmaxf(mx, al[j] + tr_s[lane][j]);
      float ss = 0.f;
      #pragma unroll
      for (int j=0;j<NTAG;++j) ss += __expf(al[j] + tr_s[lane][j] - mx);
      anew = __logf(ss) + mx + hv;
      if (!m_t) anew = al[lane];
    }
    __syncthreads();
    if (lane < NTAG) al[lane] = anew;
    __syncthreads();
  }
  if (lane < NTAG) tmp[lane] = al[lane] + tr_s[STOP_][lane];
  __syncthreads();
  float sc = 0.f; int cnt = 0;
  #pragma unroll 1
  for (int q=0;q<4;++q){
    int t = lane + 64*q;
    if (word_x[b*T_ + t] > 0){
      int yt = y[b*T_ + t];
      int yp = (t == 0) ? START_ : y[b*T_ + t - 1];
      float ev = lf[t*NTAG + yt] + lb[t*NTAG + yt] + out_b[yt];
      ev = fminf(fmaxf(ev, -1e6f), 1e6f);
      sc += ev + tr_s[yt][yp];
      cnt++;
    }
  }
  for (int off=32; off; off>>=1){
    sc += __shfl_down(sc, off);
    cnt += __shfl_down(cnt, off);
  }
  if (lane == 0){
    float mx = -3.4e38f;
    for (int j=0;j<NTAG;++j) mx = fmaxf(mx, tmp[j]);
    float ss = 0.f;
    for (int j=0;j<NTAG;++j) ss += __expf(tmp[j] - mx);
    float Z = __logf(ss) + mx;
    int last = y[b*T_ + cnt - 1];
    sc += tr_s[STOP_][last];
    out[b] = Z - sc;
  }
}

extern "C" void kernel_launch(void* const* d_in, const int* in_sizes, int n_in,
                              void* d_out, int out_size, void* d_ws, size_t ws_size,
                              hipStream_t stream) {
  (void)in_sizes; (void)n_in; (void)out_size; (void)ws_size;
  const int*   word_x  = (const int*)  d_in[0];
  const int*   char_x  = (const int*)  d_in[1];
  const int*   y       = (const int*)  d_in[2];
  const float* wemb    = (const float*)d_in[3];
  const float* cemb    = (const float*)d_in[4];
  const float* cWih    = (const float*)d_in[5];
  const float* cWhh    = (const float*)d_in[6];
  const float* cbih    = (const float*)d_in[7];
  const float* cbhh    = (const float*)d_in[8];
  const float* fWih    = (const float*)d_in[9];
  const float* fWhh    = (const float*)d_in[10];
  const float* fbih    = (const float*)d_in[11];
  const float* fbhh    = (const float*)d_in[12];
  const float* bWih    = (const float*)d_in[13];
  const float* bWhh    = (const float*)d_in[14];
  const float* bbih    = (const float*)d_in[15];
  const float* bbhh    = (const float*)d_in[16];
  const float* outW    = (const float*)d_in[17];
  const float* outb    = (const float*)d_in[18];
  const float* trans   = (const float*)d_in[19];
  float* out = (float*)d_out;

  char* ws = (char*)d_ws;
  // layout (bytes, 256-aligned):
  float*        Ec_t   = (float*)       (ws + 0);          //   204,800
  float*        c_h    = (float*)       (ws + 204800);     // 6,553,600
  ushort_t*     feat   = (ushort_t*)    (ws + 6758400);    // 13,107,200
  unsigned int* hh     = (unsigned int*)(ws + 19865600);   // 2*257*9600*4 = 19,737,600
  float*        logits = (float*)       (ws + 39603200);   // 2,621,440 -> end 42,224,640

  static const int LDS_W = 64*332*2 + 64*420*2 + 64*53*4 + 2048 + 1536;   // 113,408 B
  static const int LDS_C = 64*132*2 + 64*401*4;                           // 119,552 B
  hipFuncSetAttribute((const void*)k_word2, hipFuncAttributeMaxDynamicSharedMemorySize, LDS_W);
  hipFuncSetAttribute((const void*)k_char,  hipFuncAttributeMaxDynamicSharedMemorySize, LDS_C);

  hipLaunchKernelGGL(k_init, dim3((2*DIR_DW/4 + 255)/256), dim3(256), 0, stream, (u32x4*)hh);
  hipLaunchKernelGGL(k_ctab, dim3(200), dim3(256), 0, stream, cemb, cWih, cbih, cbhh, Ec_t);
  hipLaunchKernelGGL(k_char, dim3(256), dim3(256), LDS_C, stream, Ec_t, cWhh, char_x, c_h);
  hipLaunchKernelGGL(k_feat, dim3(6400), dim3(256), 0, stream, word_x, wemb, c_h, feat);
  hipLaunchKernelGGL(k_word2, dim3(2*NW_), dim3(512), LDS_W, stream,
                     feat, hh, fWih, fWhh, fbih, fbhh, bWih, bWhh, bbih, bbhh, word_x);
  hipLaunchKernelGGL(k_logits, dim3(NSEQ/16, 2), dim3(320), 0, stream, hh, outW, logits);
  hipLaunchKernelGGL(k_crf, dim3(64), dim3(64), 0, stream, logits, outb, trans, word_x, y, out);
}

// Round 9
// 2932.913 us; speedup vs baseline: 1.1294x; 1.0916x over previous
//
#include <hip/hip_runtime.h>

#define B_ 64
#define T_ 256
#define LC_ 16
#define CV_ 128
#define CE_ 100
#define WE_ 300
#define CH_ 100
#define WH_ 300
#define NTAG 20
#define START_ 18
#define STOP_ 19
#define NEG_ -10000.0f
#define NSEQ (B_*T_)          // 16384
#define GW (4*WH_)            // 1200
#define KF (WE_+CH_)          // 400
#define NW_ 25                // workgroups per direction in k_word2
#define UH_ 12                // hidden units per workgroup (25*12=300)
#define SLOT_DW 9600          // 25*64*6 dwords per slot
#define DIR_DW (257*SLOT_DW)  // dwords per direction
#define FLAG_STRIDE 64        // dwords between flags (256 B)
#define FLAGS_DW (2*NW_*FLAG_STRIDE)  // 3200 dwords

typedef unsigned short ushort_t;
typedef unsigned long long ull_t;
typedef __attribute__((ext_vector_type(8))) short bf16x8;
typedef __attribute__((ext_vector_type(4))) float f32x4;
typedef __attribute__((ext_vector_type(4))) unsigned int u32x4;
union BF8 { bf16x8 v; ushort_t u[8]; };

__device__ inline float bf2f(ushort_t u){ return __uint_as_float(((unsigned int)u)<<16); }
__device__ inline ushort_t f2bf(float f){
  unsigned int x = __float_as_uint(f);
  unsigned int r = (x + 0x7fffu + ((x>>16)&1u)) >> 16;
  return (ushort_t)r;
}
__device__ inline float sigm(float x){ return 1.f/(1.f+__expf(-x)); }
__device__ inline float ftanh(float x){
  float ax = fabsf(x);
  float e = __expf(-2.f*ax);
  float t = (1.f-e)/(1.f+e);
  return copysignf(t, x);
}

// ---------- 0. init: zero h slot 0 (both dirs) + flags
__global__ __launch_bounds__(256) void k_init(unsigned int* __restrict__ hh, int* __restrict__ flags){
  int idx = blockIdx.x*256 + threadIdx.x;
  if (idx < SLOT_DW) hh[idx] = 0u;
  else if (idx < 2*SLOT_DW) hh[DIR_DW + (idx - SLOT_DW)] = 0u;
  else if (idx < 2*SLOT_DW + FLAGS_DW) flags[idx - 2*SLOT_DW] = 0;
}

// ---------- 1. transposed char gate table: Ec_t[c][r] = char_emb[c].cW_ih[r] + cb_ih[r]+cb_hh[r]
__global__ __launch_bounds__(256) void k_ctab(const float* __restrict__ cemb,
    const float* __restrict__ cWih, const float* __restrict__ cbih,
    const float* __restrict__ cbhh, float* __restrict__ Ec_t){
  int idx = blockIdx.x*256 + threadIdx.x;      // 51200 = 400*128
  int r = idx >> 7, c = idx & 127;
  float a = cbih[r] + cbhh[r];
  for (int k=0;k<CE_;++k) a += cemb[c*CE_+k]*cWih[r*CE_+k];
  Ec_t[c*400 + r] = a;
}

// ---------- 2. char LSTM (MFMA): 64 seqs/WG, 4 waves; Whh frags in VGPRs
__global__ __launch_bounds__(256) void k_char(const float* __restrict__ Ec_t,
    const float* __restrict__ Whh, const int* __restrict__ char_x,
    float* __restrict__ c_h){
  extern __shared__ char csm[];
  ushort_t* h_lds = (ushort_t*)csm;              // [64][132] bf16 = 16,896 B
  float*    g_lds = (float*)(csm + 64*132*2);    // [64][401] f32  = 102,656 B
  const int tid  = threadIdx.x;
  const int lane = tid & 63;
  const int w    = tid >> 6;                     // 4 waves
  const int tb   = w*6;                          // n-tile base (w3 also does tile 24)
  bf16x8 Bf[7][4];
  {
    int ntile = (w==3) ? 7 : 6;
    for (int tt=0; tt<ntile; ++tt){
      int r = (tb+tt)*16 + (lane & 15);
      #pragma unroll
      for (int ks=0; ks<4; ++ks){
        BF8 tmp;
        #pragma unroll
        for (int j=0; j<8; ++j){
          int k = 32*ks + 8*(lane>>4) + j;
          tmp.u[j] = (k < CH_) ? f2bf(Whh[(size_t)r*CH_ + k]) : (ushort_t)0;
        }
        Bf[tt][ks] = tmp.v;
      }
    }
  }
  for (int i=tid; i<64*132; i+=256) h_lds[i] = 0;
  const int seq_l = tid & 63;
  const int us    = tid >> 6;
  const int seqg  = blockIdx.x*64 + seq_l;
  const int u0    = us*25;
  float c_r[25], h_r[25];
  #pragma unroll
  for (int j=0;j<25;++j){ c_r[j]=0.f; h_r[j]=0.f; }
  const int* cx = char_x + (size_t)seqg*LC_;
  __syncthreads();
  #pragma unroll 1
  for (int t=0; t<LC_; ++t){
    #pragma unroll
    for (int m=0; m<4; ++m){
      int abase = (16*m + (lane&15))*132 + 8*(lane>>4);
      bf16x8 a0 = *(const bf16x8*)(h_lds + abase);
      bf16x8 a1 = *(const bf16x8*)(h_lds + abase + 32);
      bf16x8 a2 = *(const bf16x8*)(h_lds + abase + 64);
      bf16x8 a3 = *(const bf16x8*)(h_lds + abase + 96);
      int rw = 16*m + 4*(lane>>4);
      #pragma unroll
      for (int tt=0; tt<6; ++tt){
        f32x4 acc = {0,0,0,0};
        acc = __builtin_amdgcn_mfma_f32_16x16x32_bf16(a0, Bf[tt][0], acc, 0,0,0);
        acc = __builtin_amdgcn_mfma_f32_16x16x32_bf16(a1, Bf[tt][1], acc, 0,0,0);
        acc = __builtin_amdgcn_mfma_f32_16x16x32_bf16(a2, Bf[tt][2], acc, 0,0,0);
        acc = __builtin_amdgcn_mfma_f32_16x16x32_bf16(a3, Bf[tt][3], acc, 0,0,0);
        int col = (tb+tt)*16 + (lane&15);
        #pragma unroll
        for (int r4=0;r4<4;++r4) g_lds[(rw+r4)*401 + col] = acc[r4];
      }
      if (w == 3){
        f32x4 acc = {0,0,0,0};
        acc = __builtin_amdgcn_mfma_f32_16x16x32_bf16(a0, Bf[6][0], acc, 0,0,0);
        acc = __builtin_amdgcn_mfma_f32_16x16x32_bf16(a1, Bf[6][1], acc, 0,0,0);
        acc = __builtin_amdgcn_mfma_f32_16x16x32_bf16(a2, Bf[6][2], acc, 0,0,0);
        acc = __builtin_amdgcn_mfma_f32_16x16x32_bf16(a3, Bf[6][3], acc, 0,0,0);
        int col = 24*16 + (lane&15);
        #pragma unroll
        for (int r4=0;r4<4;++r4) g_lds[(rw+r4)*401 + col] = acc[r4];
      }
    }
    int ch = cx[t];
    __syncthreads();
    {
      const float* ec = Ec_t + (size_t)ch*400;
      const float* gr = g_lds + seq_l*401;
      #pragma unroll
      for (int j=0;j<25;++j){
        int u = u0 + j;
        float gi = gr[u        ] + ec[u        ];
        float gf = gr[100 + u  ] + ec[100 + u  ];
        float gg = gr[200 + u  ] + ec[200 + u  ];
        float go = gr[300 + u  ] + ec[300 + u  ];
        float I = sigm(gi), F = sigm(gf), G = ftanh(gg), O = sigm(go);
        float cn = F*c_r[j] + I*G;
        float hn = O*ftanh(cn);
        if (ch > 0){ c_r[j] = cn; h_r[j] = hn; }
        h_lds[seq_l*132 + u] = f2bf(h_r[j]);
      }
    }
    __syncthreads();
  }
  #pragma unroll
  for (int j=0;j<25;++j) c_h[(size_t)seqg*CH_ + u0 + j] = h_r[j];
}

// ---------- 3. feat builder: feat[t][b][0..400) bf16 = concat(wemb[word_x], c_h)
__global__ __launch_bounds__(256) void k_feat(const int* __restrict__ word_x,
    const float* __restrict__ wemb, const float* __restrict__ c_h,
    ushort_t* __restrict__ feat){
  int gid = blockIdx.x*256 + threadIdx.x;      // 16384*100 groups of 4 cols
  int rf = gid / 100;                          // rf = t*64 + b
  int j4 = gid - rf*100;
  int k = 4*j4;
  int t = rf >> 6, b = rf & 63;
  int seq = b*T_ + t;
  float4 v;
  if (k < WE_){ int wid = word_x[seq]; v = *(const float4*)&wemb[(size_t)wid*WE_ + k]; }
  else        { v = *(const float4*)&c_h[(size_t)seq*CH_ + (k - WE_)]; }
  ushort4 u; u.x=f2bf(v.x); u.y=f2bf(v.y); u.z=f2bf(v.z); u.w=f2bf(v.w);
  *(ushort4*)&feat[(size_t)rf*KF + k] = u;
}

// ---------- 4. word LSTM: distributed recurrence, spread-flag handshake,
//              poll || feat-stage, h-load || feat-MFMA overlap.
__global__ __launch_bounds__(512, 2) void k_word2(
    const ushort_t* __restrict__ feat, unsigned int* __restrict__ hhd,
    const float* __restrict__ fWih, const float* __restrict__ fWhh,
    const float* __restrict__ fbih, const float* __restrict__ fbhh,
    const float* __restrict__ bWih, const float* __restrict__ bWhh,
    const float* __restrict__ bbih, const float* __restrict__ bbhh,
    const int* __restrict__ word_x, int* __restrict__ flags){
  extern __shared__ char smem[];
  ushort_t* h_s    = (ushort_t*)smem;                          // [64][332] bf16 = 42,496 B
  ushort_t* f_s    = (ushort_t*)(smem + 64*332*2);             // [64][420] bf16 = 53,760 B
  float*    g_s    = (float*)   (smem + 64*332*2 + 64*420*2);  // [64][53] f32   = 13,568 B
  unsigned* mask_s = (unsigned*)(smem + 64*332*2 + 64*420*2 + 64*53*4); // 2048 B
  const int tid  = threadIdx.x;
  const int lane = tid & 63;
  const int w    = tid >> 6;         // 8 waves
  const int dir  = blockIdx.x & 1;
  const int g    = blockIdx.x >> 1;  // 0..24
  const int u0   = g * UH_;
  const int tm   = w & 3;            // m-tile (batch 16-row group)
  const int grp  = w >> 2;           // 0: n-tiles {0,1}; 1: n-tile {2}
  const bool two = (grp == 0);
  const int tnb  = grp ? 2 : 0;
  const float* Wih = dir ? bWih : fWih;
  const float* Whh = dir ? bWhh : fWhh;
  const float* bi  = dir ? bbih : fbih;
  const float* bh  = dir ? bbhh : fbhh;
  int* myflags = flags + dir*NW_*FLAG_STRIDE;

  bf16x8 B2[2][13], B1[2][10];
  {
    const int kb = 8*(lane >> 4);
    #pragma unroll
    for (int ti=0; ti<2; ++ti){
      if (ti == 0 || two){
        int nl = 16*(tnb+ti) + (lane & 15);
        int r  = (nl & 3)*WH_ + u0 + (nl >> 2);   // gate q*300 + unit
        #pragma unroll
        for (int kk=0; kk<13; ++kk){
          BF8 tmp;
          #pragma unroll
          for (int j=0; j<8; ++j){
            int k = 32*kk + kb + j;
            tmp.u[j] = (k < KF) ? f2bf(Wih[(size_t)r*KF + k]) : (ushort_t)0;
          }
          B2[ti][kk] = tmp.v;
        }
        #pragma unroll
        for (int kk=0; kk<10; ++kk){
          BF8 tmp;
          #pragma unroll
          for (int j=0; j<8; ++j){
            int k = 32*kk + kb + j;
            tmp.u[j] = (k < WH_) ? f2bf(Whh[(size_t)r*WH_ + k]) : (ushort_t)0;
          }
          B1[ti][kk] = tmp.v;
        }
      }
    }
  }
  unsigned* hdl = (unsigned*)h_s;
  // ---- zero LDS K-padding: h_s dword cols 150..165, f_s shorts 400..419
  for (int idx=tid; idx<64*16; idx+=512){ int m = idx/16; hdl[m*166 + 150 + (idx - m*16)] = 0u; }
  for (int idx=tid; idx<64*20; idx+=512){ int m = idx/20; f_s[m*420 + 400 + (idx - m*20)] = 0; }
  // ---- build word-mask bitmap
  if (tid < 512){
    int row = tid >> 3, dw = tid & 7;
    const int* wp = word_x + row*T_ + dw*32;
    unsigned bits = 0u;
    #pragma unroll
    for (int j4=0; j4<8; ++j4){
      int4 v = *(const int4*)(wp + 4*j4);
      bits |= (v.x>0 ? 1u:0u) << (4*j4);
      bits |= (v.y>0 ? 1u:0u) << (4*j4+1);
      bits |= (v.z>0 ? 1u:0u) << (4*j4+2);
      bits |= (v.w>0 ? 1u:0u) << (4*j4+3);
    }
    mask_s[row*8 + dw] = bits;
  }

  const int m_u = tid & 63;
  const int up  = tid >> 6;          // 0..5 for update threads
  float4 bias_a = {0,0,0,0}, bias_b = {0,0,0,0};
  if (tid < 384){
    int u = u0 + 2*up;
    bias_a.x = bi[0*WH_+u] + bh[0*WH_+u];
    bias_a.y = bi[1*WH_+u] + bh[1*WH_+u];
    bias_a.z = bi[2*WH_+u] + bh[2*WH_+u];
    bias_a.w = bi[3*WH_+u] + bh[3*WH_+u];
    bias_b.x = bi[0*WH_+u+1] + bh[0*WH_+u+1];
    bias_b.y = bi[1*WH_+u+1] + bh[1*WH_+u+1];
    bias_b.z = bi[2*WH_+u+1] + bh[2*WH_+u+1];
    bias_b.w = bi[3*WH_+u+1] + bh[3*WH_+u+1];
  }
  float c_a=0.f, h_a=0.f, c_b=0.f, h_b=0.f;
  const int arow_f = (16*tm + (lane&15))*420 + 8*(lane>>4);
  const int arow_h = (16*tm + (lane&15))*332 + 8*(lane>>4);
  __syncthreads();

  #pragma unroll 1
  for (int s=0; s<T_; ++s){
    int t = dir ? (T_-1-s) : s;
    // -- Phase A: feat staging (waves 1-7) || flag poll (wave 0)
    if (tid >= 64){
      const ushort_t* fsrc = feat + (size_t)t*64*KF;
      for (int idx=tid-64; idx<3200; idx+=448){
        int m = idx/50, j = idx - m*50;
        uint4 v = *(const uint4*)(fsrc + m*KF + 8*j);
        *(uint4*)(f_s + m*420 + 8*j) = v;
      }
    } else if (s > 0){
      bool act = lane < NW_;
      for (int it=0; it<2000000; ++it){
        int f = act ? __hip_atomic_load(myflags + lane*FLAG_STRIDE, __ATOMIC_RELAXED, __HIP_MEMORY_SCOPE_AGENT)
                    : 0x7fffffff;
        if (__all(f >= s)) break;
        __builtin_amdgcn_s_sleep(1);
      }
    }
    __syncthreads();     // B1: f_s staged, h(s) globally published
    // -- Phase B: issue h loads, then feat-MFMA overlaps the load latency
    ull_t v[10]; int di[10];
    {
      const ull_t* hsrc = (const ull_t*)(hhd + (size_t)(dir*257 + s)*SLOT_DW);
      #pragma unroll
      for (int i=0;i<10;++i){
        int idx = tid + 512*i;
        if (i < 9 || idx < 4800){
          int gc = idx/192, r = idx - gc*192;
          int b = r/3, q = r - b*3;
          di[i] = b*166 + gc*6 + 2*q;
          v[i] = __hip_atomic_load(hsrc + idx, __ATOMIC_RELAXED, __HIP_MEMORY_SCOPE_AGENT);
        }
      }
    }
    f32x4 acc0a = {0,0,0,0}, acc0b = {0,0,0,0}, acc1a = {0,0,0,0}, acc1b = {0,0,0,0};
    #pragma unroll
    for (int kk=0; kk<13; ++kk){
      bf16x8 a = *(const bf16x8*)(f_s + arow_f + 32*kk);
      if (kk & 1){
        acc0b = __builtin_amdgcn_mfma_f32_16x16x32_bf16(a, B2[0][kk], acc0b, 0,0,0);
        if (two) acc1b = __builtin_amdgcn_mfma_f32_16x16x32_bf16(a, B2[1][kk], acc1b, 0,0,0);
      } else {
        acc0a = __builtin_amdgcn_mfma_f32_16x16x32_bf16(a, B2[0][kk], acc0a, 0,0,0);
        if (two) acc1a = __builtin_amdgcn_mfma_f32_16x16x32_bf16(a, B2[1][kk], acc1a, 0,0,0);
      }
    }
    // scatter h into LDS (waits on the loads issued above)
    #pragma unroll
    for (int i=0;i<10;++i){
      int idx = tid + 512*i;
      if (i < 9 || idx < 4800) *(ull_t*)(hdl + di[i]) = v[i];
    }
    __syncthreads();     // B2: h_s ready
    #pragma unroll
    for (int kk=0; kk<10; ++kk){
      bf16x8 a = *(const bf16x8*)(h_s + arow_h + 32*kk);
      if (kk & 1){
        acc0b = __builtin_amdgcn_mfma_f32_16x16x32_bf16(a, B1[0][kk], acc0b, 0,0,0);
        if (two) acc1b = __builtin_amdgcn_mfma_f32_16x16x32_bf16(a, B1[1][kk], acc1b, 0,0,0);
      } else {
        acc0a = __builtin_amdgcn_mfma_f32_16x16x32_bf16(a, B1[0][kk], acc0a, 0,0,0);
        if (two) acc1a = __builtin_amdgcn_mfma_f32_16x16x32_bf16(a, B1[1][kk], acc1a, 0,0,0);
      }
    }
    {
      int nb = 16*tnb + (lane & 15);
      int mr = 16*tm + 4*(lane >> 4);
      f32x4 s0 = acc0a + acc0b;
      #pragma unroll
      for (int r4=0; r4<4; ++r4) g_s[(mr+r4)*53 + nb] = s0[r4];
      if (two){
        f32x4 s1 = acc1a + acc1b;
        #pragma unroll
        for (int r4=0; r4<4; ++r4) g_s[(mr+r4)*53 + nb + 16] = s1[r4];
      }
    }
    __syncthreads();     // B3: g_s ready
    // -- update + direct scattered publish (agent-scope)
    if (tid < 384){
      int mt = (mask_s[m_u*8 + (t>>5)] >> (t&31)) & 1u;
      const float* gr = g_s + m_u*53 + 8*up;
      float ga0 = gr[0], ga1 = gr[1], ga2 = gr[2], ga3 = gr[3];
      float gb0 = gr[4], gb1 = gr[5], gb2 = gr[6], gb3 = gr[7];
      {
        float gi = sigm (ga0 + bias_a.x);
        float gf = sigm (ga1 + bias_a.y);
        float gg = ftanh(ga2 + bias_a.z);
        float go = sigm (ga3 + bias_a.w);
        float cn = gf*c_a + gi*gg;
        float hn = go*ftanh(cn);
        if (mt){ c_a = cn; h_a = hn; }
      }
      {
        float gi = sigm (gb0 + bias_b.x);
        float gf = sigm (gb1 + bias_b.y);
        float gg = ftanh(gb2 + bias_b.z);
        float go = sigm (gb3 + bias_b.w);
        float cn = gf*c_b + gi*gg;
        float hn = go*ftanh(cn);
        if (mt){ c_b = cn; h_b = hn; }
      }
      unsigned pack = (unsigned)f2bf(h_a) | ((unsigned)f2bf(h_b) << 16);
      unsigned* hdst = hhd + (size_t)(dir*257 + s + 1)*SLOT_DW + (g*64 + m_u)*6 + up;
      __hip_atomic_store(hdst, pack, __ATOMIC_RELAXED, __HIP_MEMORY_SCOPE_AGENT);
    }
    asm volatile("s_waitcnt vmcnt(0)" ::: "memory");
    __syncthreads();     // B4: all publishes drained
    if (tid == 0)
      __hip_atomic_store(myflags + g*FLAG_STRIDE, s + 1, __ATOMIC_RELAXED, __HIP_MEMORY_SCOPE_AGENT);
  }
}

// ---------- 5. logits
__global__ __launch_bounds__(320) void k_logits(const unsigned int* __restrict__ hhd,
    const float* __restrict__ outW, float* __restrict__ logits){
  __shared__ __attribute__((aligned(16))) ushort_t h_l[16][304];
  __shared__ __attribute__((aligned(16))) float    w_l[20][304];
  int tid = threadIdx.x;
  int dir = blockIdx.y;
  for (int idx=tid; idx<20*304; idx+=320){
    int tag = idx/304, k = idx - tag*304;
    w_l[tag][k] = (k < WH_) ? outW[(size_t)tag*(2*WH_) + dir*WH_ + k] : 0.f;
  }
  unsigned* hld = (unsigned*)&h_l[0][0];
  for (int idx=tid; idx<2400; idx+=320){       // 16 rows x 150 dwords
    int m = idx/150, d = idx - m*150;
    int gc = d/6, q = d - gc*6;
    int seq = blockIdx.x*16 + m;
    int b = seq >> 8, t = seq & 255;
    int slot = dir ? (T_ - t) : (t + 1);
    hld[m*152 + d] = hhd[(size_t)(dir*257 + slot)*SLOT_DW + (gc*64 + b)*6 + q];
  }
  __syncthreads();
  int sq = tid/20, tag = tid - sq*20;
  float acc = 0.f;
  #pragma unroll
  for (int jj=0; jj<75; ++jj){
    ushort_t h0 = h_l[sq][4*jj+0], h1 = h_l[sq][4*jj+1];
    ushort_t h2 = h_l[sq][4*jj+2], h3 = h_l[sq][4*jj+3];
    float4 wv = *(const float4*)&w_l[tag][4*jj];
    acc += bf2f(h0)*wv.x + bf2f(h1)*wv.y + bf2f(h2)*wv.z + bf2f(h3)*wv.w;
  }
  int seq = blockIdx.x*16 + sq;
  logits[((size_t)dir*NSEQ + seq)*NTAG + tag] = acc;
}

// ---------- 6. CRF forward + gold score
__global__ __launch_bounds__(64) void k_crf(const float* __restrict__ logits,
    const float* __restrict__ out_b, const float* __restrict__ tr,
    const int* __restrict__ word_x, const int* __restrict__ y,
    float* __restrict__ out){
  __shared__ float tr_s[NTAG][21];
  __shared__ float al[NTAG];
  __shared__ float tmp[NTAG];
  int b = blockIdx.x, lane = threadIdx.x;
  for (int idx=lane; idx<NTAG*NTAG; idx+=64) tr_s[idx/NTAG][idx%NTAG] = tr[idx];
  if (lane < NTAG) al[lane] = (lane == START_) ? 0.f : NEG_;
  __syncthreads();
  const float* lf = logits + (size_t)b*T_*NTAG;
  const float* lb = logits + (size_t)NSEQ*NTAG + (size_t)b*T_*NTAG;
  #pragma unroll 1
  for (int t=0; t<T_; ++t){
    float anew = 0.f;
    int m_t = word_x[b*T_ + t] > 0;
    if (lane < NTAG){
      float hv = lf[t*NTAG + lane] + lb[t*NTAG + lane] + out_b[lane];
      hv = fminf(fmaxf(hv, -1e6f), 1e6f);
      float mx = -3.4e38f;
      #pragma unroll
      for (int j=0;j<NTAG;++j) mx = fmaxf(mx, al[j] + tr_s[lane][j]);
      float ss = 0.f;
      #pragma unroll
      for (int j=0;j<NTAG;++j) ss += __expf(al[j] + tr_s[lane][j] - mx);
      anew = __logf(ss) + mx + hv;
      if (!m_t) anew = al[lane];
    }
    __syncthreads();
    if (lane < NTAG) al[lane] = anew;
    __syncthreads();
  }
  if (lane < NTAG) tmp[lane] = al[lane] + tr_s[STOP_][lane];
  __syncthreads();
  float sc = 0.f; int cnt = 0;
  #pragma unroll 1
  for (int q=0;q<4;++q){
    int t = lane + 64*q;
    if (word_x[b*T_ + t] > 0){
      int yt = y[b*T_ + t];
      int yp = (t == 0) ? START_ : y[b*T_ + t - 1];
      float ev = lf[t*NTAG + yt] + lb[t*NTAG + yt] + out_b[yt];
      ev = fminf(fmaxf(ev, -1e6f), 1e6f);
      sc += ev + tr_s[yt][yp];
      cnt++;
    }
  }
  for (int off=32; off; off>>=1){
    sc += __shfl_down(sc, off);
    cnt += __shfl_down(cnt, off);
  }
  if (lane == 0){
    float mx = -3.4e38f;
    for (int j=0;j<NTAG;++j) mx = fmaxf(mx, tmp[j]);
    float ss = 0.f;
    for (int j=0;j<NTAG;++j) ss += __expf(tmp[j] - mx);
    float Z = __logf(ss) + mx;
    int last = y[b*T_ + cnt - 1];
    sc += tr_s[STOP_][last];
    out[b] = Z - sc;
  }
}

extern "C" void kernel_launch(void* const* d_in, const int* in_sizes, int n_in,
                              void* d_out, int out_size, void* d_ws, size_t ws_size,
                              hipStream_t stream) {
  (void)in_sizes; (void)n_in; (void)out_size; (void)ws_size;
  const int*   word_x  = (const int*)  d_in[0];
  const int*   char_x  = (const int*)  d_in[1];
  const int*   y       = (const int*)  d_in[2];
  const float* wemb    = (const float*)d_in[3];
  const float* cemb    = (const float*)d_in[4];
  const float* cWih    = (const float*)d_in[5];
  const float* cWhh    = (const float*)d_in[6];
  const float* cbih    = (const float*)d_in[7];
  const float* cbhh    = (const float*)d_in[8];
  const float* fWih    = (const float*)d_in[9];
  const float* fWhh    = (const float*)d_in[10];
  const float* fbih    = (const float*)d_in[11];
  const float* fbhh    = (const float*)d_in[12];
  const float* bWih    = (const float*)d_in[13];
  const float* bWhh    = (const float*)d_in[14];
  const float* bbih    = (const float*)d_in[15];
  const float* bbhh    = (const float*)d_in[16];
  const float* outW    = (const float*)d_in[17];
  const float* outb    = (const float*)d_in[18];
  const float* trans   = (const float*)d_in[19];
  float* out = (float*)d_out;

  char* ws = (char*)d_ws;
  float*        Ec_t   = (float*)       (ws + 0);          //   204,800
  float*        c_h    = (float*)       (ws + 204800);     // 6,553,600
  ushort_t*     feat   = (ushort_t*)    (ws + 6758400);    // 13,107,200
  unsigned int* hh     = (unsigned int*)(ws + 19865600);   // 19,737,600
  int*          flags  = (int*)         (ws + 39603200);   // 12,800
  float*        logits = (float*)       (ws + 39616000);   // 2,621,440 -> end 42,237,440

  static const int LDS_W = 64*332*2 + 64*420*2 + 64*53*4 + 2048;   // 111,872 B
  static const int LDS_C = 64*132*2 + 64*401*4;                    // 119,552 B
  hipFuncSetAttribute((const void*)k_word2, hipFuncAttributeMaxDynamicSharedMemorySize, LDS_W);
  hipFuncSetAttribute((const void*)k_char,  hipFuncAttributeMaxDynamicSharedMemorySize, LDS_C);

  hipLaunchKernelGGL(k_init, dim3((2*SLOT_DW + FLAGS_DW + 255)/256), dim3(256), 0, stream, hh, flags);
  hipLaunchKernelGGL(k_ctab, dim3(200), dim3(256), 0, stream, cemb, cWih, cbih, cbhh, Ec_t);
  hipLaunchKernelGGL(k_char, dim3(256), dim3(256), LDS_C, stream, Ec_t, cWhh, char_x, c_h);
  hipLaunchKernelGGL(k_feat, dim3(6400), dim3(256), 0, stream, word_x, wemb, c_h, feat);
  hipLaunchKernelGGL(k_word2, dim3(2*NW_), dim3(512), LDS_W, stream,
                     feat, hh, fWih, fWhh, fbih, fbhh, bWih, bWhh, bbih, bbhh, word_x, flags);
  hipLaunchKernelGGL(k_logits, dim3(NSEQ/16, 2), dim3(320), 0, stream, hh, outW, logits);
  hipLaunchKernelGGL(k_crf, dim3(64), dim3(64), 0, stream, logits, outb, trans, word_x, y, out);
}

// Round 10
// 2897.865 us; speedup vs baseline: 1.1431x; 1.0121x over previous
//
#include <hip/hip_runtime.h>

#define B_ 64
#define T_ 256
#define LC_ 16
#define CV_ 128
#define CE_ 100
#define WE_ 300
#define CH_ 100
#define WH_ 300
#define NTAG 20
#define START_ 18
#define STOP_ 19
#define NEG_ -10000.0f
#define NSEQ (B_*T_)          // 16384
#define GW (4*WH_)            // 1200
#define KF (WE_+CH_)          // 400
#define NW_ 25                // workgroups per direction in k_word2
#define UH_ 12                // hidden units per workgroup (25*12=300)
#define SLOT_DW 9600          // 25*64*6 dwords per slot
#define DIR_DW (257*SLOT_DW)  // dwords per direction
#define FLAG_STRIDE 64        // dwords between flags (256 B)
#define FLAGS_DW (2*NW_*FLAG_STRIDE)  // 3200 dwords

typedef unsigned short ushort_t;
typedef unsigned long long ull_t;
typedef __attribute__((ext_vector_type(8))) short bf16x8;
typedef __attribute__((ext_vector_type(4))) float f32x4;
typedef __attribute__((ext_vector_type(4))) unsigned int u32x4;
union BF8 { bf16x8 v; ushort_t u[8]; };

__device__ inline float bf2f(ushort_t u){ return __uint_as_float(((unsigned int)u)<<16); }
__device__ inline ushort_t f2bf(float f){
  unsigned int x = __float_as_uint(f);
  unsigned int r = (x + 0x7fffu + ((x>>16)&1u)) >> 16;
  return (ushort_t)r;
}
__device__ inline float sigm(float x){ return 1.f/(1.f+__expf(-x)); }
__device__ inline float ftanh(float x){
  float ax = fabsf(x);
  float e = __expf(-2.f*ax);
  float t = (1.f-e)/(1.f+e);
  return copysignf(t, x);
}
// L1-bypass (L2-served) flag load: same-address re-poll must not hit stale L1.
__device__ inline int ld_flag_sc0(const int* p){
  int r;
  asm volatile("global_load_dword %0, %1, off sc0\n\ts_waitcnt vmcnt(0)"
               : "=v"(r) : "v"(p) : "memory");
  return r;
}

// ---------- 0. init: zero h slot 0 (both dirs) + flags + xcnt tickets
__global__ __launch_bounds__(256) void k_init(unsigned int* __restrict__ hh, int* __restrict__ flags){
  int idx = blockIdx.x*256 + threadIdx.x;
  if (idx < SLOT_DW) hh[idx] = 0u;
  else if (idx < 2*SLOT_DW) hh[DIR_DW + (idx - SLOT_DW)] = 0u;
  else if (idx < 2*SLOT_DW + FLAGS_DW + 8) flags[idx - 2*SLOT_DW] = 0;
}

// ---------- 1. transposed char gate table
__global__ __launch_bounds__(256) void k_ctab(const float* __restrict__ cemb,
    const float* __restrict__ cWih, const float* __restrict__ cbih,
    const float* __restrict__ cbhh, float* __restrict__ Ec_t){
  int idx = blockIdx.x*256 + threadIdx.x;      // 51200 = 400*128
  int r = idx >> 7, c = idx & 127;
  float a = cbih[r] + cbhh[r];
  for (int k=0;k<CE_;++k) a += cemb[c*CE_+k]*cWih[r*CE_+k];
  Ec_t[c*400 + r] = a;
}

// ---------- 2. char LSTM (MFMA): 64 seqs/WG, 4 waves; Whh frags in VGPRs
__global__ __launch_bounds__(256) void k_char(const float* __restrict__ Ec_t,
    const float* __restrict__ Whh, const int* __restrict__ char_x,
    float* __restrict__ c_h){
  extern __shared__ char csm[];
  ushort_t* h_lds = (ushort_t*)csm;              // [64][132] bf16 = 16,896 B
  float*    g_lds = (float*)(csm + 64*132*2);    // [64][401] f32  = 102,656 B
  const int tid  = threadIdx.x;
  const int lane = tid & 63;
  const int w    = tid >> 6;                     // 4 waves
  const int tb   = w*6;                          // n-tile base (w3 also does tile 24)
  bf16x8 Bf[7][4];
  {
    int ntile = (w==3) ? 7 : 6;
    for (int tt=0; tt<ntile; ++tt){
      int r = (tb+tt)*16 + (lane & 15);
      #pragma unroll
      for (int ks=0; ks<4; ++ks){
        BF8 tmp;
        #pragma unroll
        for (int j=0; j<8; ++j){
          int k = 32*ks + 8*(lane>>4) + j;
          tmp.u[j] = (k < CH_) ? f2bf(Whh[(size_t)r*CH_ + k]) : (ushort_t)0;
        }
        Bf[tt][ks] = tmp.v;
      }
    }
  }
  for (int i=tid; i<64*132; i+=256) h_lds[i] = 0;
  const int seq_l = tid & 63;
  const int us    = tid >> 6;
  const int seqg  = blockIdx.x*64 + seq_l;
  const int u0    = us*25;
  float c_r[25], h_r[25];
  #pragma unroll
  for (int j=0;j<25;++j){ c_r[j]=0.f; h_r[j]=0.f; }
  const int* cx = char_x + (size_t)seqg*LC_;
  __syncthreads();
  #pragma unroll 1
  for (int t=0; t<LC_; ++t){
    #pragma unroll
    for (int m=0; m<4; ++m){
      int abase = (16*m + (lane&15))*132 + 8*(lane>>4);
      bf16x8 a0 = *(const bf16x8*)(h_lds + abase);
      bf16x8 a1 = *(const bf16x8*)(h_lds + abase + 32);
      bf16x8 a2 = *(const bf16x8*)(h_lds + abase + 64);
      bf16x8 a3 = *(const bf16x8*)(h_lds + abase + 96);
      int rw = 16*m + 4*(lane>>4);
      #pragma unroll
      for (int tt=0; tt<6; ++tt){
        f32x4 acc = {0,0,0,0};
        acc = __builtin_amdgcn_mfma_f32_16x16x32_bf16(a0, Bf[tt][0], acc, 0,0,0);
        acc = __builtin_amdgcn_mfma_f32_16x16x32_bf16(a1, Bf[tt][1], acc, 0,0,0);
        acc = __builtin_amdgcn_mfma_f32_16x16x32_bf16(a2, Bf[tt][2], acc, 0,0,0);
        acc = __builtin_amdgcn_mfma_f32_16x16x32_bf16(a3, Bf[tt][3], acc, 0,0,0);
        int col = (tb+tt)*16 + (lane&15);
        #pragma unroll
        for (int r4=0;r4<4;++r4) g_lds[(rw+r4)*401 + col] = acc[r4];
      }
      if (w == 3){
        f32x4 acc = {0,0,0,0};
        acc = __builtin_amdgcn_mfma_f32_16x16x32_bf16(a0, Bf[6][0], acc, 0,0,0);
        acc = __builtin_amdgcn_mfma_f32_16x16x32_bf16(a1, Bf[6][1], acc, 0,0,0);
        acc = __builtin_amdgcn_mfma_f32_16x16x32_bf16(a2, Bf[6][2], acc, 0,0,0);
        acc = __builtin_amdgcn_mfma_f32_16x16x32_bf16(a3, Bf[6][3], acc, 0,0,0);
        int col = 24*16 + (lane&15);
        #pragma unroll
        for (int r4=0;r4<4;++r4) g_lds[(rw+r4)*401 + col] = acc[r4];
      }
    }
    int ch = cx[t];
    __syncthreads();
    {
      const float* ec = Ec_t + (size_t)ch*400;
      const float* gr = g_lds + seq_l*401;
      #pragma unroll
      for (int j=0;j<25;++j){
        int u = u0 + j;
        float gi = gr[u        ] + ec[u        ];
        float gf = gr[100 + u  ] + ec[100 + u  ];
        float gg = gr[200 + u  ] + ec[200 + u  ];
        float go = gr[300 + u  ] + ec[300 + u  ];
        float I = sigm(gi), F = sigm(gf), G = ftanh(gg), O = sigm(go);
        float cn = F*c_r[j] + I*G;
        float hn = O*ftanh(cn);
        if (ch > 0){ c_r[j] = cn; h_r[j] = hn; }
        h_lds[seq_l*132 + u] = f2bf(h_r[j]);
      }
    }
    __syncthreads();
  }
  #pragma unroll
  for (int j=0;j<25;++j) c_h[(size_t)seqg*CH_ + u0 + j] = h_r[j];
}

// ---------- 3. feat builder
__global__ __launch_bounds__(256) void k_feat(const int* __restrict__ word_x,
    const float* __restrict__ wemb, const float* __restrict__ c_h,
    ushort_t* __restrict__ feat){
  int gid = blockIdx.x*256 + threadIdx.x;      // 16384*100 groups of 4 cols
  int rf = gid / 100;                          // rf = t*64 + b
  int j4 = gid - rf*100;
  int k = 4*j4;
  int t = rf >> 6, b = rf & 63;
  int seq = b*T_ + t;
  float4 v;
  if (k < WE_){ int wid = word_x[seq]; v = *(const float4*)&wemb[(size_t)wid*WE_ + k]; }
  else        { v = *(const float4*)&c_h[(size_t)seq*CH_ + (k - WE_)]; }
  ushort4 u; u.x=f2bf(v.x); u.y=f2bf(v.y); u.z=f2bf(v.z); u.w=f2bf(v.w);
  *(ushort4*)&feat[(size_t)rf*KF + k] = u;
}

// ---------- 4. word LSTM: XCD-pinned distributed recurrence; intra-XCD L2 handshake.
__global__ __launch_bounds__(512, 2) void k_word2(
    const ushort_t* __restrict__ feat, unsigned int* __restrict__ hhd,
    const float* __restrict__ fWih, const float* __restrict__ fWhh,
    const float* __restrict__ fbih, const float* __restrict__ fbhh,
    const float* __restrict__ bWih, const float* __restrict__ bWhh,
    const float* __restrict__ bbih, const float* __restrict__ bbhh,
    const int* __restrict__ word_x, int* __restrict__ flags, int* __restrict__ xcnt){
  __shared__ int claim_s[2];
  extern __shared__ char smem[];
  ushort_t* h_s    = (ushort_t*)smem;                          // [64][332] bf16 = 42,496 B
  ushort_t* f_s    = (ushort_t*)(smem + 64*332*2);             // [64][420] bf16 = 53,760 B
  float*    g_s    = (float*)   (smem + 64*332*2 + 64*420*2);  // [64][53] f32   = 13,568 B
  unsigned* mask_s = (unsigned*)(smem + 64*332*2 + 64*420*2 + 64*53*4); // 2048 B
  const int tid  = threadIdx.x;
  const int lane = tid & 63;
  const int w    = tid >> 6;         // 8 waves
  // ---- XCD-pinned work claim: dir0 = first 25 WGs on XCC0, dir1 = first 25 on XCC1
  if (tid == 0){
    unsigned xcc;
    asm volatile("s_getreg_b32 %0, hwreg(HW_REG_XCC_ID)" : "=s"(xcc));
    xcc &= 7u;
    int rank = -1;
    if (xcc < 2u) rank = atomicAdd(&xcnt[xcc], 1);
    claim_s[0] = (int)xcc;
    claim_s[1] = rank;
  }
  __syncthreads();
  const int xcc  = claim_s[0];
  const int rank = claim_s[1];
  if (xcc >= 2 || rank < 0 || rank >= NW_) return;
  const int dir = xcc;
  const int g   = rank;              // 0..24
  const int u0  = g * UH_;
  const int tm   = w & 3;            // m-tile (batch 16-row group)
  const int grp  = w >> 2;           // 0: n-tiles {0,1}; 1: n-tile {2}
  const bool two = (grp == 0);
  const int tnb  = grp ? 2 : 0;
  const float* Wih = dir ? bWih : fWih;
  const float* Whh = dir ? bWhh : fWhh;
  const float* bi  = dir ? bbih : fbih;
  const float* bh  = dir ? bbhh : fbhh;
  int* myflags = flags + dir*NW_*FLAG_STRIDE;

  bf16x8 B2[2][13], B1[2][10];
  {
    const int kb = 8*(lane >> 4);
    #pragma unroll
    for (int ti=0; ti<2; ++ti){
      if (ti == 0 || two){
        int nl = 16*(tnb+ti) + (lane & 15);
        int r  = (nl & 3)*WH_ + u0 + (nl >> 2);   // gate q*300 + unit
        #pragma unroll
        for (int kk=0; kk<13; ++kk){
          BF8 tmp;
          #pragma unroll
          for (int j=0; j<8; ++j){
            int k = 32*kk + kb + j;
            tmp.u[j] = (k < KF) ? f2bf(Wih[(size_t)r*KF + k]) : (ushort_t)0;
          }
          B2[ti][kk] = tmp.v;
        }
        #pragma unroll
        for (int kk=0; kk<10; ++kk){
          BF8 tmp;
          #pragma unroll
          for (int j=0; j<8; ++j){
            int k = 32*kk + kb + j;
            tmp.u[j] = (k < WH_) ? f2bf(Whh[(size_t)r*WH_ + k]) : (ushort_t)0;
          }
          B1[ti][kk] = tmp.v;
        }
      }
    }
  }
  unsigned* hdl = (unsigned*)h_s;
  // ---- zero LDS K-padding: h_s dword cols 150..165, f_s shorts 400..419
  for (int idx=tid; idx<64*16; idx+=512){ int m = idx/16; hdl[m*166 + 150 + (idx - m*16)] = 0u; }
  for (int idx=tid; idx<64*20; idx+=512){ int m = idx/20; f_s[m*420 + 400 + (idx - m*20)] = 0; }
  // ---- build word-mask bitmap
  if (tid < 512){
    int row = tid >> 3, dw = tid & 7;
    const int* wp = word_x + row*T_ + dw*32;
    unsigned bits = 0u;
    #pragma unroll
    for (int j4=0; j4<8; ++j4){
      int4 v = *(const int4*)(wp + 4*j4);
      bits |= (v.x>0 ? 1u:0u) << (4*j4);
      bits |= (v.y>0 ? 1u:0u) << (4*j4+1);
      bits |= (v.z>0 ? 1u:0u) << (4*j4+2);
      bits |= (v.w>0 ? 1u:0u) << (4*j4+3);
    }
    mask_s[row*8 + dw] = bits;
  }

  const int m_u = tid & 63;
  const int up  = tid >> 6;          // 0..5 for update threads
  float4 bias_a = {0,0,0,0}, bias_b = {0,0,0,0};
  if (tid < 384){
    int u = u0 + 2*up;
    bias_a.x = bi[0*WH_+u] + bh[0*WH_+u];
    bias_a.y = bi[1*WH_+u] + bh[1*WH_+u];
    bias_a.z = bi[2*WH_+u] + bh[2*WH_+u];
    bias_a.w = bi[3*WH_+u] + bh[3*WH_+u];
    bias_b.x = bi[0*WH_+u+1] + bh[0*WH_+u+1];
    bias_b.y = bi[1*WH_+u+1] + bh[1*WH_+u+1];
    bias_b.z = bi[2*WH_+u+1] + bh[2*WH_+u+1];
    bias_b.w = bi[3*WH_+u+1] + bh[3*WH_+u+1];
  }
  float c_a=0.f, h_a=0.f, c_b=0.f, h_b=0.f;
  const int arow_f = (16*tm + (lane&15))*420 + 8*(lane>>4);
  const int arow_h = (16*tm + (lane&15))*332 + 8*(lane>>4);
  __syncthreads();

  #pragma unroll 1
  for (int s=0; s<T_; ++s){
    int t = dir ? (T_-1-s) : s;
    // -- stage feat(t) (all threads, plain cached loads)
    {
      const ushort_t* fsrc = feat + (size_t)t*64*KF;
      for (int idx=tid; idx<3200; idx+=512){
        int m = idx/50, j = idx - m*50;
        uint4 v = *(const uint4*)(fsrc + m*KF + 8*j);
        *(uint4*)(f_s + m*420 + 8*j) = v;
      }
    }
    // -- wait until all WGs of this dir published slot s (sc0 polls, local L2)
    if (w == 0 && s > 0){
      bool act = lane < NW_;
      const int* fp = myflags + lane*FLAG_STRIDE;
      for (int it=0; it<500000; ++it){
        int f = act ? ld_flag_sc0(fp) : 0x7fffffff;
        if (__all(f >= s)) break;
        __builtin_amdgcn_s_sleep(1);
      }
    }
    __syncthreads();
    // -- stage h(s): plain loads (first-touch lines -> L1 miss -> local-L2 hit)
    {
      const ull_t* hsrc = (const ull_t*)(hhd + (size_t)(dir*257 + s)*SLOT_DW);
      ull_t v[10]; int di[10];
      #pragma unroll
      for (int i=0;i<10;++i){
        int idx = tid + 512*i;
        if (i < 9 || idx < 4800){
          int gc = idx/192, r = idx - gc*192;
          int b = r/3, q = r - b*3;
          di[i] = b*166 + gc*6 + 2*q;
          v[i] = hsrc[idx];
        }
      }
      #pragma unroll
      for (int i=0;i<10;++i){
        int idx = tid + 512*i;
        if (i < 9 || idx < 4800) *(ull_t*)(hdl + di[i]) = v[i];
      }
    }
    __syncthreads();
    // -- MFMA: gates(64 x 48-slice) = feat*Wih^T + h*Whh^T
    f32x4 acc0a = {0,0,0,0}, acc0b = {0,0,0,0}, acc1a = {0,0,0,0}, acc1b = {0,0,0,0};
    #pragma unroll
    for (int kk=0; kk<13; ++kk){
      bf16x8 a = *(const bf16x8*)(f_s + arow_f + 32*kk);
      if (kk & 1){
        acc0b = __builtin_amdgcn_mfma_f32_16x16x32_bf16(a, B2[0][kk], acc0b, 0,0,0);
        if (two) acc1b = __builtin_amdgcn_mfma_f32_16x16x32_bf16(a, B2[1][kk], acc1b, 0,0,0);
      } else {
        acc0a = __builtin_amdgcn_mfma_f32_16x16x32_bf16(a, B2[0][kk], acc0a, 0,0,0);
        if (two) acc1a = __builtin_amdgcn_mfma_f32_16x16x32_bf16(a, B2[1][kk], acc1a, 0,0,0);
      }
    }
    #pragma unroll
    for (int kk=0; kk<10; ++kk){
      bf16x8 a = *(const bf16x8*)(h_s + arow_h + 32*kk);
      if (kk & 1){
        acc0b = __builtin_amdgcn_mfma_f32_16x16x32_bf16(a, B1[0][kk], acc0b, 0,0,0);
        if (two) acc1b = __builtin_amdgcn_mfma_f32_16x16x32_bf16(a, B1[1][kk], acc1b, 0,0,0);
      } else {
        acc0a = __builtin_amdgcn_mfma_f32_16x16x32_bf16(a, B1[0][kk], acc0a, 0,0,0);
        if (two) acc1a = __builtin_amdgcn_mfma_f32_16x16x32_bf16(a, B1[1][kk], acc1a, 0,0,0);
      }
    }
    {
      int nb = 16*tnb + (lane & 15);
      int mr = 16*tm + 4*(lane >> 4);
      f32x4 s0 = acc0a + acc0b;
      #pragma unroll
      for (int r4=0; r4<4; ++r4) g_s[(mr+r4)*53 + nb] = s0[r4];
      if (two){
        f32x4 s1 = acc1a + acc1b;
        #pragma unroll
        for (int r4=0; r4<4; ++r4) g_s[(mr+r4)*53 + nb + 16] = s1[r4];
      }
    }
    __syncthreads();
    // -- update + publish (plain stores -> local L2)
    if (tid < 384){
      int mt = (mask_s[m_u*8 + (t>>5)] >> (t&31)) & 1u;
      const float* gr = g_s + m_u*53 + 8*up;
      float4 ga = *(const float4*)(gr);
      float4 gb = *(const float4*)(gr + 4);
      {
        float gi = sigm (ga.x + bias_a.x);
        float gf = sigm (ga.y + bias_a.y);
        float gg = ftanh(ga.z + bias_a.z);
        float go = sigm (ga.w + bias_a.w);
        float cn = gf*c_a + gi*gg;
        float hn = go*ftanh(cn);
        if (mt){ c_a = cn; h_a = hn; }
      }
      {
        float gi = sigm (gb.x + bias_b.x);
        float gf = sigm (gb.y + bias_b.y);
        float gg = ftanh(gb.z + bias_b.z);
        float go = sigm (gb.w + bias_b.w);
        float cn = gf*c_b + gi*gg;
        float hn = go*ftanh(cn);
        if (mt){ c_b = cn; h_b = hn; }
      }
      unsigned pack = (unsigned)f2bf(h_a) | ((unsigned)f2bf(h_b) << 16);
      hhd[(size_t)(dir*257 + s + 1)*SLOT_DW + (g*64 + m_u)*6 + up] = pack;
    }
    asm volatile("s_waitcnt vmcnt(0)" ::: "memory");   // h stores committed to L2
    __syncthreads();                                   // all waves drained
    if (tid == 0)
      *(volatile int*)(myflags + g*FLAG_STRIDE) = s + 1;
  }
}

// ---------- 5. logits
__global__ __launch_bounds__(320) void k_logits(const unsigned int* __restrict__ hhd,
    const float* __restrict__ outW, float* __restrict__ logits){
  __shared__ __attribute__((aligned(16))) ushort_t h_l[16][304];
  __shared__ __attribute__((aligned(16))) float    w_l[20][304];
  int tid = threadIdx.x;
  int dir = blockIdx.y;
  for (int idx=tid; idx<20*304; idx+=320){
    int tag = idx/304, k = idx - tag*304;
    w_l[tag][k] = (k < WH_) ? outW[(size_t)tag*(2*WH_) + dir*WH_ + k] : 0.f;
  }
  unsigned* hld = (unsigned*)&h_l[0][0];
  for (int idx=tid; idx<2400; idx+=320){       // 16 rows x 150 dwords
    int m = idx/150, d = idx - m*150;
    int gc = d/6, q = d - gc*6;
    int seq = blockIdx.x*16 + m;
    int b = seq >> 8, t = seq & 255;
    int slot = dir ? (T_ - t) : (t + 1);
    hld[m*152 + d] = hhd[(size_t)(dir*257 + slot)*SLOT_DW + (gc*64 + b)*6 + q];
  }
  __syncthreads();
  int sq = tid/20, tag = tid - sq*20;
  float acc = 0.f;
  #pragma unroll
  for (int jj=0; jj<75; ++jj){
    ushort_t h0 = h_l[sq][4*jj+0], h1 = h_l[sq][4*jj+1];
    ushort_t h2 = h_l[sq][4*jj+2], h3 = h_l[sq][4*jj+3];
    float4 wv = *(const float4*)&w_l[tag][4*jj];
    acc += bf2f(h0)*wv.x + bf2f(h1)*wv.y + bf2f(h2)*wv.z + bf2f(h3)*wv.w;
  }
  int seq = blockIdx.x*16 + sq;
  logits[((size_t)dir*NSEQ + seq)*NTAG + tag] = acc;
}

// ---------- 6. CRF forward + gold score
__global__ __launch_bounds__(64) void k_crf(const float* __restrict__ logits,
    const float* __restrict__ out_b, const float* __restrict__ tr,
    const int* __restrict__ word_x, const int* __restrict__ y,
    float* __restrict__ out){
  __shared__ float tr_s[NTAG][21];
  __shared__ float al[NTAG];
  __shared__ float tmp[NTAG];
  int b = blockIdx.x, lane = threadIdx.x;
  for (int idx=lane; idx<NTAG*NTAG; idx+=64) tr_s[idx/NTAG][idx%NTAG] = tr[idx];
  if (lane < NTAG) al[lane] = (lane == START_) ? 0.f : NEG_;
  __syncthreads();
  const float* lf = logits + (size_t)b*T_*NTAG;
  const float* lb = logits + (size_t)NSEQ*NTAG + (size_t)b*T_*NTAG;
  #pragma unroll 1
  for (int t=0; t<T_; ++t){
    float anew = 0.f;
    int m_t = word_x[b*T_ + t] > 0;
    if (lane < NTAG){
      float hv = lf[t*NTAG + lane] + lb[t*NTAG + lane] + out_b[lane];
      hv = fminf(fmaxf(hv, -1e6f), 1e6f);
      float mx = -3.4e38f;
      #pragma unroll
      for (int j=0;j<NTAG;++j) mx = fmaxf(mx, al[j] + tr_s[lane][j]);
      float ss = 0.f;
      #pragma unroll
      for (int j=0;j<NTAG;++j) ss += __expf(al[j] + tr_s[lane][j] - mx);
      anew = __logf(ss) + mx + hv;
      if (!m_t) anew = al[lane];
    }
    __syncthreads();
    if (lane < NTAG) al[lane] = anew;
    __syncthreads();
  }
  if (lane < NTAG) tmp[lane] = al[lane] + tr_s[STOP_][lane];
  __syncthreads();
  float sc = 0.f; int cnt = 0;
  #pragma unroll 1
  for (int q=0;q<4;++q){
    int t = lane + 64*q;
    if (word_x[b*T_ + t] > 0){
      int yt = y[b*T_ + t];
      int yp = (t == 0) ? START_ : y[b*T_ + t - 1];
      float ev = lf[t*NTAG + yt] + lb[t*NTAG + yt] + out_b[yt];
      ev = fminf(fmaxf(ev, -1e6f), 1e6f);
      sc += ev + tr_s[yt][yp];
      cnt++;
    }
  }
  for (int off=32; off; off>>=1){
    sc += __shfl_down(sc, off);
    cnt += __shfl_down(cnt, off);
  }
  if (lane == 0){
    float mx = -3.4e38f;
    for (int j=0;j<NTAG;++j) mx = fmaxf(mx, tmp[j]);
    float ss = 0.f;
    for (int j=0;j<NTAG;++j) ss += __expf(tmp[j] - mx);
    float Z = __logf(ss) + mx;
    int last = y[b*T_ + cnt - 1];
    sc += tr_s[STOP_][last];
    out[b] = Z - sc;
  }
}

extern "C" void kernel_launch(void* const* d_in, const int* in_sizes, int n_in,
                              void* d_out, int out_size, void* d_ws, size_t ws_size,
                              hipStream_t stream) {
  (void)in_sizes; (void)n_in; (void)out_size; (void)ws_size;
  const int*   word_x  = (const int*)  d_in[0];
  const int*   char_x  = (const int*)  d_in[1];
  const int*   y       = (const int*)  d_in[2];
  const float* wemb    = (const float*)d_in[3];
  const float* cemb    = (const float*)d_in[4];
  const float* cWih    = (const float*)d_in[5];
  const float* cWhh    = (const float*)d_in[6];
  const float* cbih    = (const float*)d_in[7];
  const float* cbhh    = (const float*)d_in[8];
  const float* fWih    = (const float*)d_in[9];
  const float* fWhh    = (const float*)d_in[10];
  const float* fbih    = (const float*)d_in[11];
  const float* fbhh    = (const float*)d_in[12];
  const float* bWih    = (const float*)d_in[13];
  const float* bWhh    = (const float*)d_in[14];
  const float* bbih    = (const float*)d_in[15];
  const float* bbhh    = (const float*)d_in[16];
  const float* outW    = (const float*)d_in[17];
  const float* outb    = (const float*)d_in[18];
  const float* trans   = (const float*)d_in[19];
  float* out = (float*)d_out;

  char* ws = (char*)d_ws;
  float*        Ec_t   = (float*)       (ws + 0);          //   204,800
  float*        c_h    = (float*)       (ws + 204800);     // 6,553,600
  ushort_t*     feat   = (ushort_t*)    (ws + 6758400);    // 13,107,200
  unsigned int* hh     = (unsigned int*)(ws + 19865600);   // 19,737,600
  int*          flags  = (int*)         (ws + 39603200);   // 3200+8 ints
  int*          xcnt   = flags + FLAGS_DW;                 // 8 ints
  float*        logits = (float*)       (ws + 39616256);   // 2,621,440 -> end 42,237,696

  static const int LDS_W = 64*332*2 + 64*420*2 + 64*53*4 + 2048;   // 111,872 B
  static const int LDS_C = 64*132*2 + 64*401*4;                    // 119,552 B
  hipFuncSetAttribute((const void*)k_word2, hipFuncAttributeMaxDynamicSharedMemorySize, LDS_W);
  hipFuncSetAttribute((const void*)k_char,  hipFuncAttributeMaxDynamicSharedMemorySize, LDS_C);

  hipLaunchKernelGGL(k_init, dim3((2*SLOT_DW + FLAGS_DW + 8 + 255)/256), dim3(256), 0, stream, hh, flags);
  hipLaunchKernelGGL(k_ctab, dim3(200), dim3(256), 0, stream, cemb, cWih, cbih, cbhh, Ec_t);
  hipLaunchKernelGGL(k_char, dim3(256), dim3(256), LDS_C, stream, Ec_t, cWhh, char_x, c_h);
  hipLaunchKernelGGL(k_feat, dim3(6400), dim3(256), 0, stream, word_x, wemb, c_h, feat);
  hipLaunchKernelGGL(k_word2, dim3(1024), dim3(512), LDS_W, stream,
                     feat, hh, fWih, fWhh, fbih, fbhh, bWih, bWhh, bbih, bbhh, word_x, flags, xcnt);
  hipLaunchKernelGGL(k_logits, dim3(NSEQ/16, 2), dim3(320), 0, stream, hh, outW, logits);
  hipLaunchKernelGGL(k_crf, dim3(64), dim3(64), 0, stream, logits, outb, trans, word_x, y, out);
}

// Round 11
// 2218.565 us; speedup vs baseline: 1.4931x; 1.3062x over previous
//
#include <hip/hip_runtime.h>

#define B_ 64
#define T_ 256
#define LC_ 16
#define CV_ 128
#define CE_ 100
#define WE_ 300
#define CH_ 100
#define WH_ 300
#define NTAG 20
#define START_ 18
#define STOP_ 19
#define NEG_ -10000.0f
#define NSEQ (B_*T_)          // 16384
#define GW (4*WH_)            // 1200
#define KF (WE_+CH_)          // 400
#define NW_ 25                // workgroups per direction in k_word2
#define UH_ 12                // hidden units per workgroup (25*12=300)
#define SLOT_DW 9600          // 25*64*6 dwords per slot
#define DIR_DW (257*SLOT_DW)  // dwords per direction

typedef unsigned short ushort_t;
typedef unsigned long long ull_t;
typedef __attribute__((ext_vector_type(8))) short bf16x8;
typedef __attribute__((ext_vector_type(4))) float f32x4;
union BF8 { bf16x8 v; ushort_t u[8]; };

__device__ inline float bf2f(ushort_t u){ return __uint_as_float(((unsigned int)u)<<16); }
__device__ inline ushort_t f2bf(float f){
  unsigned int x = __float_as_uint(f);
  unsigned int r = (x + 0x7fffu + ((x>>16)&1u)) >> 16;
  return (ushort_t)r;
}
__device__ inline float sigm(float x){ return 1.f/(1.f+__expf(-x)); }
__device__ inline float ftanh(float x){
  float ax = fabsf(x);
  float e = __expf(-2.f*ax);
  float t = (1.f-e)/(1.f+e);
  return copysignf(t, x);
}

// ---------- 0. init: zero h slot 0 (both dirs) + flags
__global__ __launch_bounds__(256) void k_init(unsigned int* __restrict__ hh, int* __restrict__ flags){
  int idx = blockIdx.x*256 + threadIdx.x;
  if (idx < SLOT_DW) hh[idx] = 0u;
  else if (idx < 2*SLOT_DW) hh[DIR_DW + (idx - SLOT_DW)] = 0u;
  else if (idx < 2*SLOT_DW + 64) flags[idx - 2*SLOT_DW] = 0;
}

// ---------- 1. transposed char gate table: Ec_t[c][r] = char_emb[c].cW_ih[r] + cb_ih[r]+cb_hh[r]
__global__ __launch_bounds__(256) void k_ctab(const float* __restrict__ cemb,
    const float* __restrict__ cWih, const float* __restrict__ cbih,
    const float* __restrict__ cbhh, float* __restrict__ Ec_t){
  int idx = blockIdx.x*256 + threadIdx.x;      // 51200 = 400*128
  int r = idx >> 7, c = idx & 127;
  float a = cbih[r] + cbhh[r];
  for (int k=0;k<CE_;++k) a += cemb[c*CE_+k]*cWih[r*CE_+k];
  Ec_t[c*400 + r] = a;
}

// ---------- 2. char LSTM (MFMA): 64 seqs/WG, 4 waves; Whh frags in VGPRs
__global__ __launch_bounds__(256) void k_char(const float* __restrict__ Ec_t,
    const float* __restrict__ Whh, const int* __restrict__ char_x,
    float* __restrict__ c_h){
  extern __shared__ char csm[];
  ushort_t* h_lds = (ushort_t*)csm;              // [64][132] bf16 = 16,896 B
  float*    g_lds = (float*)(csm + 64*132*2);    // [64][401] f32  = 102,656 B
  const int tid  = threadIdx.x;
  const int lane = tid & 63;
  const int w    = tid >> 6;                     // 4 waves
  const int tb   = w*6;                          // n-tile base (w3 also does tile 24)
  bf16x8 Bf[7][4];
  {
    int ntile = (w==3) ? 7 : 6;
    for (int tt=0; tt<ntile; ++tt){
      int r = (tb+tt)*16 + (lane & 15);
      #pragma unroll
      for (int ks=0; ks<4; ++ks){
        BF8 tmp;
        #pragma unroll
        for (int j=0; j<8; ++j){
          int k = 32*ks + 8*(lane>>4) + j;
          tmp.u[j] = (k < CH_) ? f2bf(Whh[(size_t)r*CH_ + k]) : (ushort_t)0;
        }
        Bf[tt][ks] = tmp.v;
      }
    }
  }
  for (int i=tid; i<64*132; i+=256) h_lds[i] = 0;
  const int seq_l = tid & 63;
  const int us    = tid >> 6;
  const int seqg  = blockIdx.x*64 + seq_l;
  const int u0    = us*25;
  float c_r[25], h_r[25];
  #pragma unroll
  for (int j=0;j<25;++j){ c_r[j]=0.f; h_r[j]=0.f; }
  const int* cx = char_x + (size_t)seqg*LC_;
  __syncthreads();
  #pragma unroll 1
  for (int t=0; t<LC_; ++t){
    #pragma unroll
    for (int m=0; m<4; ++m){
      int abase = (16*m + (lane&15))*132 + 8*(lane>>4);
      bf16x8 a0 = *(const bf16x8*)(h_lds + abase);
      bf16x8 a1 = *(const bf16x8*)(h_lds + abase + 32);
      bf16x8 a2 = *(const bf16x8*)(h_lds + abase + 64);
      bf16x8 a3 = *(const bf16x8*)(h_lds + abase + 96);
      int rw = 16*m + 4*(lane>>4);
      #pragma unroll
      for (int tt=0; tt<6; ++tt){
        f32x4 acc = {0,0,0,0};
        acc = __builtin_amdgcn_mfma_f32_16x16x32_bf16(a0, Bf[tt][0], acc, 0,0,0);
        acc = __builtin_amdgcn_mfma_f32_16x16x32_bf16(a1, Bf[tt][1], acc, 0,0,0);
        acc = __builtin_amdgcn_mfma_f32_16x16x32_bf16(a2, Bf[tt][2], acc, 0,0,0);
        acc = __builtin_amdgcn_mfma_f32_16x16x32_bf16(a3, Bf[tt][3], acc, 0,0,0);
        int col = (tb+tt)*16 + (lane&15);
        #pragma unroll
        for (int r4=0;r4<4;++r4) g_lds[(rw+r4)*401 + col] = acc[r4];
      }
      if (w == 3){
        f32x4 acc = {0,0,0,0};
        acc = __builtin_amdgcn_mfma_f32_16x16x32_bf16(a0, Bf[6][0], acc, 0,0,0);
        acc = __builtin_amdgcn_mfma_f32_16x16x32_bf16(a1, Bf[6][1], acc, 0,0,0);
        acc = __builtin_amdgcn_mfma_f32_16x16x32_bf16(a2, Bf[6][2], acc, 0,0,0);
        acc = __builtin_amdgcn_mfma_f32_16x16x32_bf16(a3, Bf[6][3], acc, 0,0,0);
        int col = 24*16 + (lane&15);
        #pragma unroll
        for (int r4=0;r4<4;++r4) g_lds[(rw+r4)*401 + col] = acc[r4];
      }
    }
    int ch = cx[t];
    __syncthreads();
    {
      const float* ec = Ec_t + (size_t)ch*400;
      const float* gr = g_lds + seq_l*401;
      #pragma unroll
      for (int j=0;j<25;++j){
        int u = u0 + j;
        float gi = gr[u        ] + ec[u        ];
        float gf = gr[100 + u  ] + ec[100 + u  ];
        float gg = gr[200 + u  ] + ec[200 + u  ];
        float go = gr[300 + u  ] + ec[300 + u  ];
        float I = sigm(gi), F = sigm(gf), G = ftanh(gg), O = sigm(go);
        float cn = F*c_r[j] + I*G;
        float hn = O*ftanh(cn);
        if (ch > 0){ c_r[j] = cn; h_r[j] = hn; }
        h_lds[seq_l*132 + u] = f2bf(h_r[j]);
      }
    }
    __syncthreads();
  }
  #pragma unroll
  for (int j=0;j<25;++j) c_h[(size_t)seqg*CH_ + u0 + j] = h_r[j];
}

// ---------- 3. feat builder: feat[t][b][0..400) bf16 = concat(wemb[word_x], c_h)
__global__ __launch_bounds__(256) void k_feat(const int* __restrict__ word_x,
    const float* __restrict__ wemb, const float* __restrict__ c_h,
    ushort_t* __restrict__ feat){
  int gid = blockIdx.x*256 + threadIdx.x;      // 16384*100 groups of 4 cols
  int rf = gid / 100;                          // rf = t*64 + b
  int j4 = gid - rf*100;
  int k = 4*j4;
  int t = rf >> 6, b = rf & 63;
  int seq = b*T_ + t;
  float4 v;
  if (k < WE_){ int wid = word_x[seq]; v = *(const float4*)&wemb[(size_t)wid*WE_ + k]; }
  else        { v = *(const float4*)&c_h[(size_t)seq*CH_ + (k - WE_)]; }
  ushort4 u; u.x=f2bf(v.x); u.y=f2bf(v.y); u.z=f2bf(v.z); u.w=f2bf(v.w);
  *(ushort4*)&feat[(size_t)rf*KF + k] = u;
}

// ---------- 4. word LSTM: distributed recurrence, persistent weights in VGPRs,
//              MFMA gates, per-WG flag handshake (exact r6 structure — fastest measured).
__global__ __launch_bounds__(512, 2) void k_word2(
    const ushort_t* __restrict__ feat, unsigned int* __restrict__ hhd,
    const float* __restrict__ fWih, const float* __restrict__ fWhh,
    const float* __restrict__ fbih, const float* __restrict__ fbhh,
    const float* __restrict__ bWih, const float* __restrict__ bWhh,
    const float* __restrict__ bbih, const float* __restrict__ bbhh,
    const int* __restrict__ word_x, int* __restrict__ flags){
  extern __shared__ char smem[];
  ushort_t* h_s    = (ushort_t*)smem;                          // [64][328] bf16 = 41984 B
  ushort_t* f_s    = (ushort_t*)(smem + 64*328*2);             // [64][416] bf16 = 53248 B
  float*    g_s    = (float*)   (smem + 64*328*2 + 64*416*2);  // [64][52] f32   = 13312 B
  unsigned* mask_s = (unsigned*)(smem + 64*328*2 + 64*416*2 + 64*52*4); // [64][8] = 2048 B
  const int tid  = threadIdx.x;
  const int lane = tid & 63;
  const int w    = tid >> 6;         // 8 waves
  const int dir  = blockIdx.x & 1;
  const int g    = blockIdx.x >> 1;  // 0..24
  const int u0   = g * UH_;
  const int tm   = w & 3;            // m-tile (batch 16-row group)
  const int grp  = w >> 2;           // 0: n-tiles {0,1}; 1: n-tile {2}
  const bool two = (grp == 0);
  const int tnb  = grp ? 2 : 0;
  const float* Wih = dir ? bWih : fWih;
  const float* Whh = dir ? bWhh : fWhh;
  const float* bi  = dir ? bbih : fbih;
  const float* bh  = dir ? bbhh : fbhh;
  int* myflags = flags + dir*32;

  // ---- persistent B fragments (W_ih: 13 k-slabs; W_hh: 10 k-slabs)
  bf16x8 B2[2][13], B1[2][10];
  {
    const int kb = 8*(lane >> 4);
    #pragma unroll
    for (int ti=0; ti<2; ++ti){
      if (ti == 0 || two){
        int nl = 16*(tnb+ti) + (lane & 15);
        int r  = (nl & 3)*WH_ + u0 + (nl >> 2);   // gate q*300 + unit
        #pragma unroll
        for (int kk=0; kk<13; ++kk){
          BF8 tmp;
          #pragma unroll
          for (int j=0; j<8; ++j){
            int k = 32*kk + kb + j;
            tmp.u[j] = (k < KF) ? f2bf(Wih[(size_t)r*KF + k]) : (ushort_t)0;
          }
          B2[ti][kk] = tmp.v;
        }
        #pragma unroll
        for (int kk=0; kk<10; ++kk){
          BF8 tmp;
          #pragma unroll
          for (int j=0; j<8; ++j){
            int k = 32*kk + kb + j;
            tmp.u[j] = (k < WH_) ? f2bf(Whh[(size_t)r*WH_ + k]) : (ushort_t)0;
          }
          B1[ti][kk] = tmp.v;
        }
      }
    }
  }
  unsigned* hdl = (unsigned*)h_s;
  // ---- zero LDS K-padding: h_s dword cols 150..163, f_s shorts 400..415
  for (int idx=tid; idx<64*14; idx+=512){ int m = idx/14; hdl[m*164 + 150 + (idx - m*14)] = 0u; }
  for (int idx=tid; idx<64*16; idx+=512){ f_s[(idx>>4)*416 + 400 + (idx & 15)] = 0; }
  // ---- build word-mask bitmap: mask_s[b][t>>5] bit (t&31)
  if (tid < 512){
    int row = tid >> 3, dw = tid & 7;
    const int* wp = word_x + row*T_ + dw*32;
    unsigned bits = 0u;
    #pragma unroll
    for (int j4=0; j4<8; ++j4){
      int4 v = *(const int4*)(wp + 4*j4);
      bits |= (v.x>0 ? 1u:0u) << (4*j4);
      bits |= (v.y>0 ? 1u:0u) << (4*j4+1);
      bits |= (v.z>0 ? 1u:0u) << (4*j4+2);
      bits |= (v.w>0 ? 1u:0u) << (4*j4+3);
    }
    mask_s[row*8 + dw] = bits;
  }

  // ---- update threads: tid<384: m_u = tid&63, up = tid>>6 (units u0+2up, u0+2up+1)
  const int m_u = tid & 63;
  const int up  = tid >> 6;          // 0..5 for update threads
  float4 bias_a = {0,0,0,0}, bias_b = {0,0,0,0};
  if (tid < 384){
    int u = u0 + 2*up;
    bias_a.x = bi[0*WH_+u] + bh[0*WH_+u];
    bias_a.y = bi[1*WH_+u] + bh[1*WH_+u];
    bias_a.z = bi[2*WH_+u] + bh[2*WH_+u];
    bias_a.w = bi[3*WH_+u] + bh[3*WH_+u];
    bias_b.x = bi[0*WH_+u+1] + bh[0*WH_+u+1];
    bias_b.y = bi[1*WH_+u+1] + bh[1*WH_+u+1];
    bias_b.z = bi[2*WH_+u+1] + bh[2*WH_+u+1];
    bias_b.w = bi[3*WH_+u+1] + bh[3*WH_+u+1];
  }
  float c_a=0.f, h_a=0.f, c_b=0.f, h_b=0.f;
  const int arow_f = (16*tm + (lane&15))*416 + 8*(lane>>4);
  const int arow_h = (16*tm + (lane&15))*328 + 8*(lane>>4);
  __syncthreads();

  #pragma unroll 1
  for (int s=0; s<T_; ++s){
    int t = dir ? (T_-1-s) : s;
    // -- stage feat(t) first: latency hides under the poll
    {
      const ushort_t* fsrc = feat + (size_t)t*64*KF;
      for (int idx=tid; idx<3200; idx+=512){
        int m = idx/50, j = idx - m*50;
        uint4 v = *(const uint4*)(fsrc + m*KF + 8*j);
        *(uint4*)(f_s + m*416 + 8*j) = v;
      }
    }
    // -- wait until all WGs of this dir published slot s (parallel flag poll, no RMW)
    if (w == 0 && s > 0){
      bool act = lane < NW_;
      for (int it=0; it<2000000; ++it){
        int f = act ? __hip_atomic_load(myflags + lane, __ATOMIC_RELAXED, __HIP_MEMORY_SCOPE_AGENT)
                    : 0x7fffffff;
        if (__all(f >= s)) break;
        __builtin_amdgcn_s_sleep(1);
      }
    }
    __syncthreads();
    // -- stage h(s): 4800 contiguous qwords, agent-scope loads, chunked layout
    {
      const ull_t* hsrc = (const ull_t*)(hhd + (size_t)(dir*257 + s)*SLOT_DW);
      ull_t v[10]; int di[10];
      #pragma unroll
      for (int i=0;i<10;++i){
        int idx = tid + 512*i;
        if (i < 9 || idx < 4800){
          int gc = idx / 192;
          int r  = idx - gc*192;
          int b  = r/3, q = r - b*3;
          di[i] = b*164 + gc*6 + 2*q;
          v[i] = __hip_atomic_load(hsrc + idx, __ATOMIC_RELAXED, __HIP_MEMORY_SCOPE_AGENT);
        }
      }
      #pragma unroll
      for (int i=0;i<10;++i){
        int idx = tid + 512*i;
        if (i < 9 || idx < 4800) *(ull_t*)(hdl + di[i]) = v[i];
      }
    }
    __syncthreads();
    // -- MFMA: gates(64 x 48-slice) = feat*Wih^T + h*Whh^T
    f32x4 acc0a = {0,0,0,0}, acc0b = {0,0,0,0}, acc1a = {0,0,0,0}, acc1b = {0,0,0,0};
    #pragma unroll
    for (int kk=0; kk<13; ++kk){
      bf16x8 a = *(const bf16x8*)(f_s + arow_f + 32*kk);
      if (kk & 1){
        acc0b = __builtin_amdgcn_mfma_f32_16x16x32_bf16(a, B2[0][kk], acc0b, 0,0,0);
        if (two) acc1b = __builtin_amdgcn_mfma_f32_16x16x32_bf16(a, B2[1][kk], acc1b, 0,0,0);
      } else {
        acc0a = __builtin_amdgcn_mfma_f32_16x16x32_bf16(a, B2[0][kk], acc0a, 0,0,0);
        if (two) acc1a = __builtin_amdgcn_mfma_f32_16x16x32_bf16(a, B2[1][kk], acc1a, 0,0,0);
      }
    }
    #pragma unroll
    for (int kk=0; kk<10; ++kk){
      bf16x8 a = *(const bf16x8*)(h_s + arow_h + 32*kk);
      if (kk & 1){
        acc0b = __builtin_amdgcn_mfma_f32_16x16x32_bf16(a, B1[0][kk], acc0b, 0,0,0);
        if (two) acc1b = __builtin_amdgcn_mfma_f32_16x16x32_bf16(a, B1[1][kk], acc1b, 0,0,0);
      } else {
        acc0a = __builtin_amdgcn_mfma_f32_16x16x32_bf16(a, B1[0][kk], acc0a, 0,0,0);
        if (two) acc1a = __builtin_amdgcn_mfma_f32_16x16x32_bf16(a, B1[1][kk], acc1a, 0,0,0);
      }
    }
    // -- write gate fragments to g_s
    {
      int nb = 16*tnb + (lane & 15);
      int mr = 16*tm + 4*(lane >> 4);
      f32x4 s0 = acc0a + acc0b;
      #pragma unroll
      for (int r4=0; r4<4; ++r4) g_s[(mr+r4)*52 + nb] = s0[r4];
      if (two){
        f32x4 s1 = acc1a + acc1b;
        #pragma unroll
        for (int r4=0; r4<4; ++r4) g_s[(mr+r4)*52 + nb + 16] = s1[r4];
      }
    }
    __syncthreads();
    // -- elementwise LSTM update + publish carried h (own contiguous chunk)
    if (tid < 384){
      int mt = (mask_s[m_u*8 + (t>>5)] >> (t&31)) & 1u;
      float4 ga = *(const float4*)(g_s + m_u*52 + 8*up);
      float4 gb = *(const float4*)(g_s + m_u*52 + 8*up + 4);
      {
        float gi = sigm (ga.x + bias_a.x);
        float gf = sigm (ga.y + bias_a.y);
        float gg = ftanh(ga.z + bias_a.z);
        float go = sigm (ga.w + bias_a.w);
        float cn = gf*c_a + gi*gg;
        float hn = go*ftanh(cn);
        if (mt){ c_a = cn; h_a = hn; }
      }
      {
        float gi = sigm (gb.x + bias_b.x);
        float gf = sigm (gb.y + bias_b.y);
        float gg = ftanh(gb.z + bias_b.z);
        float go = sigm (gb.w + bias_b.w);
        float cn = gf*c_b + gi*gg;
        float hn = go*ftanh(cn);
        if (mt){ c_b = cn; h_b = hn; }
      }
      unsigned pack = (unsigned)f2bf(h_a) | ((unsigned)f2bf(h_b) << 16);
      unsigned* hdst = hhd + (size_t)(dir*257 + s + 1)*SLOT_DW + (g*64 + m_u)*6 + up;
      __hip_atomic_store(hdst, pack, __ATOMIC_RELAXED, __HIP_MEMORY_SCOPE_AGENT);
    }
    asm volatile("s_waitcnt vmcnt(0)" ::: "memory");
    __syncthreads();   // all waves' stores drained
    if (tid == 0)
      __hip_atomic_store(myflags + g, s + 1, __ATOMIC_RELAXED, __HIP_MEMORY_SCOPE_AGENT);
  }
}

// ---------- 5. logits: logits[dir][seq][tag] = h_dir(t) . outW[tag][dir*300..]
__global__ __launch_bounds__(320) void k_logits(const unsigned int* __restrict__ hhd,
    const float* __restrict__ outW, float* __restrict__ logits){
  __shared__ __attribute__((aligned(16))) ushort_t h_l[16][304];
  __shared__ __attribute__((aligned(16))) float    w_l[20][304];
  int tid = threadIdx.x;
  int dir = blockIdx.y;
  for (int idx=tid; idx<20*304; idx+=320){
    int tag = idx/304, k = idx - tag*304;
    w_l[tag][k] = (k < WH_) ? outW[(size_t)tag*(2*WH_) + dir*WH_ + k] : 0.f;
  }
  unsigned* hld = (unsigned*)&h_l[0][0];
  for (int idx=tid; idx<2400; idx+=320){       // 16 rows x 150 dwords
    int m = idx/150, d = idx - m*150;
    int gc = d/6, q = d - gc*6;
    int seq = blockIdx.x*16 + m;
    int b = seq >> 8, t = seq & 255;
    int slot = dir ? (T_ - t) : (t + 1);
    hld[m*152 + d] = hhd[(size_t)(dir*257 + slot)*SLOT_DW + (gc*64 + b)*6 + q];
  }
  __syncthreads();
  int sq = tid/20, tag = tid - sq*20;
  float acc = 0.f;
  #pragma unroll
  for (int jj=0; jj<75; ++jj){
    ushort_t h0 = h_l[sq][4*jj+0], h1 = h_l[sq][4*jj+1];
    ushort_t h2 = h_l[sq][4*jj+2], h3 = h_l[sq][4*jj+3];
    float4 wv = *(const float4*)&w_l[tag][4*jj];
    acc += bf2f(h0)*wv.x + bf2f(h1)*wv.y + bf2f(h2)*wv.z + bf2f(h3)*wv.w;
  }
  int seq = blockIdx.x*16 + sq;
  logits[((size_t)dir*NSEQ + seq)*NTAG + tag] = acc;
}

// ---------- 6. CRF forward + gold score (one wave per batch element)
__global__ __launch_bounds__(64) void k_crf(const float* __restrict__ logits,
    const float* __restrict__ out_b, const float* __restrict__ tr,
    const int* __restrict__ word_x, const int* __restrict__ y,
    float* __restrict__ out){
  __shared__ float tr_s[NTAG][21];
  __shared__ float al[NTAG];
  __shared__ float tmp[NTAG];
  int b = blockIdx.x, lane = threadIdx.x;
  for (int idx=lane; idx<NTAG*NTAG; idx+=64) tr_s[idx/NTAG][idx%NTAG] = tr[idx];
  if (lane < NTAG) al[lane] = (lane == START_) ? 0.f : NEG_;
  __syncthreads();
  const float* lf = logits + (size_t)b*T_*NTAG;
  const float* lb = logits + (size_t)NSEQ*NTAG + (size_t)b*T_*NTAG;
  #pragma unroll 1
  for (int t=0; t<T_; ++t){
    float anew = 0.f;
    int m_t = word_x[b*T_ + t] > 0;
    if (lane < NTAG){
      float hv = lf[t*NTAG + lane] + lb[t*NTAG + lane] + out_b[lane];
      hv = fminf(fmaxf(hv, -1e6f), 1e6f);
      float mx = -3.4e38f;
      #pragma unroll
      for (int j=0;j<NTAG;++j) mx = fmaxf(mx, al[j] + tr_s[lane][j]);
      float ss = 0.f;
      #pragma unroll
      for (int j=0;j<NTAG;++j) ss += __expf(al[j] + tr_s[lane][j] - mx);
      anew = __logf(ss) + mx + hv;
      if (!m_t) anew = al[lane];
    }
    __syncthreads();
    if (lane < NTAG) al[lane] = anew;
    __syncthreads();
  }
  if (lane < NTAG) tmp[lane] = al[lane] + tr_s[STOP_][lane];
  __syncthreads();
  float sc = 0.f; int cnt = 0;
  #pragma unroll 1
  for (int q=0;q<4;++q){
    int t = lane + 64*q;
    if (word_x[b*T_ + t] > 0){
      int yt = y[b*T_ + t];
      int yp = (t == 0) ? START_ : y[b*T_ + t - 1];
      float ev = lf[t*NTAG + yt] + lb[t*NTAG + yt] + out_b[yt];
      ev = fminf(fmaxf(ev, -1e6f), 1e6f);
      sc += ev + tr_s[yt][yp];
      cnt++;
    }
  }
  for (int off=32; off; off>>=1){
    sc += __shfl_down(sc, off);
    cnt += __shfl_down(cnt, off);
  }
  if (lane == 0){
    float mx = -3.4e38f;
    for (int j=0;j<NTAG;++j) mx = fmaxf(mx, tmp[j]);
    float ss = 0.f;
    for (int j=0;j<NTAG;++j) ss += __expf(tmp[j] - mx);
    float Z = __logf(ss) + mx;
    int last = y[b*T_ + cnt - 1];
    sc += tr_s[STOP_][last];
    out[b] = Z - sc;
  }
}

extern "C" void kernel_launch(void* const* d_in, const int* in_sizes, int n_in,
                              void* d_out, int out_size, void* d_ws, size_t ws_size,
                              hipStream_t stream) {
  (void)in_sizes; (void)n_in; (void)out_size; (void)ws_size;
  const int*   word_x  = (const int*)  d_in[0];
  const int*   char_x  = (const int*)  d_in[1];
  const int*   y       = (const int*)  d_in[2];
  const float* wemb    = (const float*)d_in[3];
  const float* cemb    = (const float*)d_in[4];
  const float* cWih    = (const float*)d_in[5];
  const float* cWhh    = (const float*)d_in[6];
  const float* cbih    = (const float*)d_in[7];
  const float* cbhh    = (const float*)d_in[8];
  const float* fWih    = (const float*)d_in[9];
  const float* fWhh    = (const float*)d_in[10];
  const float* fbih    = (const float*)d_in[11];
  const float* fbhh    = (const float*)d_in[12];
  const float* bWih    = (const float*)d_in[13];
  const float* bWhh    = (const float*)d_in[14];
  const float* bbih    = (const float*)d_in[15];
  const float* bbhh    = (const float*)d_in[16];
  const float* outW    = (const float*)d_in[17];
  const float* outb    = (const float*)d_in[18];
  const float* trans   = (const float*)d_in[19];
  float* out = (float*)d_out;

  char* ws = (char*)d_ws;
  // layout (bytes, 256-aligned):
  float*        Ec_t   = (float*)       (ws + 0);          //   204,800
  float*        c_h    = (float*)       (ws + 204800);     // 6,553,600
  ushort_t*     feat   = (ushort_t*)    (ws + 6758400);    // 13,107,200
  unsigned int* hh     = (unsigned int*)(ws + 19865600);   // 19,737,600
  int*          flags  = (int*)         (ws + 39603200);   // 64 ints = 256
  float*        logits = (float*)       (ws + 39603456);   // 2,621,440 -> end 42,224,896

  static const int LDS_W = 64*328*2 + 64*416*2 + 64*52*4 + 64*8*4;   // 110,592 B
  static const int LDS_C = 64*132*2 + 64*401*4;                      // 119,552 B
  hipFuncSetAttribute((const void*)k_word2, hipFuncAttributeMaxDynamicSharedMemorySize, LDS_W);
  hipFuncSetAttribute((const void*)k_char,  hipFuncAttributeMaxDynamicSharedMemorySize, LDS_C);

  hipLaunchKernelGGL(k_init, dim3((2*SLOT_DW + 64 + 255)/256), dim3(256), 0, stream, hh, flags);
  hipLaunchKernelGGL(k_ctab, dim3(200), dim3(256), 0, stream, cemb, cWih, cbih, cbhh, Ec_t);
  hipLaunchKernelGGL(k_char, dim3(256), dim3(256), LDS_C, stream, Ec_t, cWhh, char_x, c_h);
  hipLaunchKernelGGL(k_feat, dim3(6400), dim3(256), 0, stream, word_x, wemb, c_h, feat);
  hipLaunchKernelGGL(k_word2, dim3(2*NW_), dim3(512), LDS_W, stream,
                     feat, hh, fWih, fWhh, fbih, fbhh, bWih, bWhh, bbih, bbhh, word_x, flags);
  hipLaunchKernelGGL(k_logits, dim3(NSEQ/16, 2), dim3(320), 0, stream, hh, outW, logits);
  hipLaunchKernelGGL(k_crf, dim3(64), dim3(64), 0, stream, logits, outb, trans, word_x, y, out);
}

// Round 12
// 2210.922 us; speedup vs baseline: 1.4983x; 1.0035x over previous
//
#include <hip/hip_runtime.h>

#define B_ 64
#define T_ 256
#define LC_ 16
#define CV_ 128
#define CE_ 100
#define WE_ 300
#define CH_ 100
#define WH_ 300
#define NTAG 20
#define START_ 18
#define STOP_ 19
#define NEG_ -10000.0f
#define NSEQ (B_*T_)          // 16384
#define GW (4*WH_)            // 1200
#define KF (WE_+CH_)          // 400
#define NW_ 25                // workgroups per direction in k_word2
#define UH_ 12                // hidden units per workgroup (25*12=300)
#define SLOT_DW 9600          // 25*64*6 dwords per slot
#define DIR_DW (257*SLOT_DW)  // dwords per direction

typedef unsigned short ushort_t;
typedef unsigned long long ull_t;
typedef __attribute__((ext_vector_type(8))) short bf16x8;
typedef __attribute__((ext_vector_type(4))) float f32x4;
union BF8 { bf16x8 v; ushort_t u[8]; };

__device__ inline float bf2f(ushort_t u){ return __uint_as_float(((unsigned int)u)<<16); }
__device__ inline ushort_t f2bf(float f){
  unsigned int x = __float_as_uint(f);
  unsigned int r = (x + 0x7fffu + ((x>>16)&1u)) >> 16;
  return (ushort_t)r;
}
__device__ inline float sigm(float x){ return 1.f/(1.f+__expf(-x)); }
__device__ inline float ftanh(float x){
  float ax = fabsf(x);
  float e = __expf(-2.f*ax);
  float t = (1.f-e)/(1.f+e);
  return copysignf(t, x);
}

// ---------- 0. prep: [blocks 0..75] zero h slot 0 + flags; [76..275] char gate table
__global__ __launch_bounds__(256) void k_prep(unsigned int* __restrict__ hh, int* __restrict__ flags,
    const float* __restrict__ cemb, const float* __restrict__ cWih,
    const float* __restrict__ cbih, const float* __restrict__ cbhh, float* __restrict__ Ec_t){
  int bid = blockIdx.x;
  if (bid < 76){
    int idx = bid*256 + threadIdx.x;
    if (idx < SLOT_DW) hh[idx] = 0u;
    else if (idx < 2*SLOT_DW) hh[DIR_DW + (idx - SLOT_DW)] = 0u;
    else if (idx < 2*SLOT_DW + 64) flags[idx - 2*SLOT_DW] = 0;
  } else {
    int idx = (bid - 76)*256 + threadIdx.x;      // 51200 = 400*128
    int r = idx >> 7, c = idx & 127;
    float a = cbih[r] + cbhh[r];
    for (int k=0;k<CE_;++k) a += cemb[c*CE_+k]*cWih[r*CE_+k];
    Ec_t[c*400 + r] = a;
  }
}

// ---------- 2. char LSTM (MFMA): 64 seqs/WG, 4 waves; Whh frags in VGPRs
__global__ __launch_bounds__(256) void k_char(const float* __restrict__ Ec_t,
    const float* __restrict__ Whh, const int* __restrict__ char_x,
    float* __restrict__ c_h){
  extern __shared__ char csm[];
  ushort_t* h_lds = (ushort_t*)csm;              // [64][132] bf16 = 16,896 B
  float*    g_lds = (float*)(csm + 64*132*2);    // [64][401] f32  = 102,656 B
  const int tid  = threadIdx.x;
  const int lane = tid & 63;
  const int w    = tid >> 6;                     // 4 waves
  const int tb   = w*6;                          // n-tile base (w3 also does tile 24)
  bf16x8 Bf[7][4];
  {
    int ntile = (w==3) ? 7 : 6;
    for (int tt=0; tt<ntile; ++tt){
      int r = (tb+tt)*16 + (lane & 15);
      #pragma unroll
      for (int ks=0; ks<4; ++ks){
        BF8 tmp;
        #pragma unroll
        for (int j=0; j<8; ++j){
          int k = 32*ks + 8*(lane>>4) + j;
          tmp.u[j] = (k < CH_) ? f2bf(Whh[(size_t)r*CH_ + k]) : (ushort_t)0;
        }
        Bf[tt][ks] = tmp.v;
      }
    }
  }
  for (int i=tid; i<64*132; i+=256) h_lds[i] = 0;
  const int seq_l = tid & 63;
  const int us    = tid >> 6;
  const int seqg  = blockIdx.x*64 + seq_l;
  const int u0    = us*25;
  float c_r[25], h_r[25];
  #pragma unroll
  for (int j=0;j<25;++j){ c_r[j]=0.f; h_r[j]=0.f; }
  const int* cx = char_x + (size_t)seqg*LC_;
  __syncthreads();
  #pragma unroll 1
  for (int t=0; t<LC_; ++t){
    #pragma unroll
    for (int m=0; m<4; ++m){
      int abase = (16*m + (lane&15))*132 + 8*(lane>>4);
      bf16x8 a0 = *(const bf16x8*)(h_lds + abase);
      bf16x8 a1 = *(const bf16x8*)(h_lds + abase + 32);
      bf16x8 a2 = *(const bf16x8*)(h_lds + abase + 64);
      bf16x8 a3 = *(const bf16x8*)(h_lds + abase + 96);
      int rw = 16*m + 4*(lane>>4);
      #pragma unroll
      for (int tt=0; tt<6; ++tt){
        f32x4 acc = {0,0,0,0};
        acc = __builtin_amdgcn_mfma_f32_16x16x32_bf16(a0, Bf[tt][0], acc, 0,0,0);
        acc = __builtin_amdgcn_mfma_f32_16x16x32_bf16(a1, Bf[tt][1], acc, 0,0,0);
        acc = __builtin_amdgcn_mfma_f32_16x16x32_bf16(a2, Bf[tt][2], acc, 0,0,0);
        acc = __builtin_amdgcn_mfma_f32_16x16x32_bf16(a3, Bf[tt][3], acc, 0,0,0);
        int col = (tb+tt)*16 + (lane&15);
        #pragma unroll
        for (int r4=0;r4<4;++r4) g_lds[(rw+r4)*401 + col] = acc[r4];
      }
      if (w == 3){
        f32x4 acc = {0,0,0,0};
        acc = __builtin_amdgcn_mfma_f32_16x16x32_bf16(a0, Bf[6][0], acc, 0,0,0);
        acc = __builtin_amdgcn_mfma_f32_16x16x32_bf16(a1, Bf[6][1], acc, 0,0,0);
        acc = __builtin_amdgcn_mfma_f32_16x16x32_bf16(a2, Bf[6][2], acc, 0,0,0);
        acc = __builtin_amdgcn_mfma_f32_16x16x32_bf16(a3, Bf[6][3], acc, 0,0,0);
        int col = 24*16 + (lane&15);
        #pragma unroll
        for (int r4=0;r4<4;++r4) g_lds[(rw+r4)*401 + col] = acc[r4];
      }
    }
    int ch = cx[t];
    __syncthreads();
    {
      const float* ec = Ec_t + (size_t)ch*400;
      const float* gr = g_lds + seq_l*401;
      #pragma unroll
      for (int j=0;j<25;++j){
        int u = u0 + j;
        float gi = gr[u        ] + ec[u        ];
        float gf = gr[100 + u  ] + ec[100 + u  ];
        float gg = gr[200 + u  ] + ec[200 + u  ];
        float go = gr[300 + u  ] + ec[300 + u  ];
        float I = sigm(gi), F = sigm(gf), G = ftanh(gg), O = sigm(go);
        float cn = F*c_r[j] + I*G;
        float hn = O*ftanh(cn);
        if (ch > 0){ c_r[j] = cn; h_r[j] = hn; }
        h_lds[seq_l*132 + u] = f2bf(h_r[j]);
      }
    }
    __syncthreads();
  }
  #pragma unroll
  for (int j=0;j<25;++j) c_h[(size_t)seqg*CH_ + u0 + j] = h_r[j];
}

// ---------- 3. feat builder: feat[t][b][0..400) bf16 = concat(wemb[word_x], c_h)
__global__ __launch_bounds__(256) void k_feat(const int* __restrict__ word_x,
    const float* __restrict__ wemb, const float* __restrict__ c_h,
    ushort_t* __restrict__ feat){
  int gid = blockIdx.x*256 + threadIdx.x;      // 16384*100 groups of 4 cols
  int rf = gid / 100;                          // rf = t*64 + b
  int j4 = gid - rf*100;
  int k = 4*j4;
  int t = rf >> 6, b = rf & 63;
  int seq = b*T_ + t;
  float4 v;
  if (k < WE_){ int wid = word_x[seq]; v = *(const float4*)&wemb[(size_t)wid*WE_ + k]; }
  else        { v = *(const float4*)&c_h[(size_t)seq*CH_ + (k - WE_)]; }
  ushort4 u; u.x=f2bf(v.x); u.y=f2bf(v.y); u.z=f2bf(v.z); u.w=f2bf(v.w);
  *(ushort4*)&feat[(size_t)rf*KF + k] = u;
}

// ---------- 4. word LSTM: distributed recurrence, persistent weights in VGPRs,
//              MFMA gates, per-WG flag handshake (exact r6/r11 structure — fastest measured).
__global__ __launch_bounds__(512, 2) void k_word2(
    const ushort_t* __restrict__ feat, unsigned int* __restrict__ hhd,
    const float* __restrict__ fWih, const float* __restrict__ fWhh,
    const float* __restrict__ fbih, const float* __restrict__ fbhh,
    const float* __restrict__ bWih, const float* __restrict__ bWhh,
    const float* __restrict__ bbih, const float* __restrict__ bbhh,
    const int* __restrict__ word_x, int* __restrict__ flags){
  extern __shared__ char smem[];
  ushort_t* h_s    = (ushort_t*)smem;                          // [64][328] bf16 = 41984 B
  ushort_t* f_s    = (ushort_t*)(smem + 64*328*2);             // [64][416] bf16 = 53248 B
  float*    g_s    = (float*)   (smem + 64*328*2 + 64*416*2);  // [64][52] f32   = 13312 B
  unsigned* mask_s = (unsigned*)(smem + 64*328*2 + 64*416*2 + 64*52*4); // [64][8] = 2048 B
  const int tid  = threadIdx.x;
  const int lane = tid & 63;
  const int w    = tid >> 6;         // 8 waves
  const int dir  = blockIdx.x & 1;
  const int g    = blockIdx.x >> 1;  // 0..24
  const int u0   = g * UH_;
  const int tm   = w & 3;            // m-tile (batch 16-row group)
  const int grp  = w >> 2;           // 0: n-tiles {0,1}; 1: n-tile {2}
  const bool two = (grp == 0);
  const int tnb  = grp ? 2 : 0;
  const float* Wih = dir ? bWih : fWih;
  const float* Whh = dir ? bWhh : fWhh;
  const float* bi  = dir ? bbih : fbih;
  const float* bh  = dir ? bbhh : fbhh;
  int* myflags = flags + dir*32;

  // ---- persistent B fragments (W_ih: 13 k-slabs; W_hh: 10 k-slabs)
  bf16x8 B2[2][13], B1[2][10];
  {
    const int kb = 8*(lane >> 4);
    #pragma unroll
    for (int ti=0; ti<2; ++ti){
      if (ti == 0 || two){
        int nl = 16*(tnb+ti) + (lane & 15);
        int r  = (nl & 3)*WH_ + u0 + (nl >> 2);   // gate q*300 + unit
        #pragma unroll
        for (int kk=0; kk<13; ++kk){
          BF8 tmp;
          #pragma unroll
          for (int j=0; j<8; ++j){
            int k = 32*kk + kb + j;
            tmp.u[j] = (k < KF) ? f2bf(Wih[(size_t)r*KF + k]) : (ushort_t)0;
          }
          B2[ti][kk] = tmp.v;
        }
        #pragma unroll
        for (int kk=0; kk<10; ++kk){
          BF8 tmp;
          #pragma unroll
          for (int j=0; j<8; ++j){
            int k = 32*kk + kb + j;
            tmp.u[j] = (k < WH_) ? f2bf(Whh[(size_t)r*WH_ + k]) : (ushort_t)0;
          }
          B1[ti][kk] = tmp.v;
        }
      }
    }
  }
  unsigned* hdl = (unsigned*)h_s;
  // ---- zero LDS K-padding: h_s dword cols 150..163, f_s shorts 400..415
  for (int idx=tid; idx<64*14; idx+=512){ int m = idx/14; hdl[m*164 + 150 + (idx - m*14)] = 0u; }
  for (int idx=tid; idx<64*16; idx+=512){ f_s[(idx>>4)*416 + 400 + (idx & 15)] = 0; }
  // ---- build word-mask bitmap: mask_s[b][t>>5] bit (t&31)
  if (tid < 512){
    int row = tid >> 3, dw = tid & 7;
    const int* wp = word_x + row*T_ + dw*32;
    unsigned bits = 0u;
    #pragma unroll
    for (int j4=0; j4<8; ++j4){
      int4 v = *(const int4*)(wp + 4*j4);
      bits |= (v.x>0 ? 1u:0u) << (4*j4);
      bits |= (v.y>0 ? 1u:0u) << (4*j4+1);
      bits |= (v.z>0 ? 1u:0u) << (4*j4+2);
      bits |= (v.w>0 ? 1u:0u) << (4*j4+3);
    }
    mask_s[row*8 + dw] = bits;
  }

  // ---- update threads: tid<384: m_u = tid&63, up = tid>>6 (units u0+2up, u0+2up+1)
  const int m_u = tid & 63;
  const int up  = tid >> 6;          // 0..5 for update threads
  float4 bias_a = {0,0,0,0}, bias_b = {0,0,0,0};
  if (tid < 384){
    int u = u0 + 2*up;
    bias_a.x = bi[0*WH_+u] + bh[0*WH_+u];
    bias_a.y = bi[1*WH_+u] + bh[1*WH_+u];
    bias_a.z = bi[2*WH_+u] + bh[2*WH_+u];
    bias_a.w = bi[3*WH_+u] + bh[3*WH_+u];
    bias_b.x = bi[0*WH_+u+1] + bh[0*WH_+u+1];
    bias_b.y = bi[1*WH_+u+1] + bh[1*WH_+u+1];
    bias_b.z = bi[2*WH_+u+1] + bh[2*WH_+u+1];
    bias_b.w = bi[3*WH_+u+1] + bh[3*WH_+u+1];
  }
  float c_a=0.f, h_a=0.f, c_b=0.f, h_b=0.f;
  const int arow_f = (16*tm + (lane&15))*416 + 8*(lane>>4);
  const int arow_h = (16*tm + (lane&15))*328 + 8*(lane>>4);
  __syncthreads();

  #pragma unroll 1
  for (int s=0; s<T_; ++s){
    int t = dir ? (T_-1-s) : s;
    // -- stage feat(t) first: latency hides under the poll
    {
      const ushort_t* fsrc = feat + (size_t)t*64*KF;
      for (int idx=tid; idx<3200; idx+=512){
        int m = idx/50, j = idx - m*50;
        uint4 v = *(const uint4*)(fsrc + m*KF + 8*j);
        *(uint4*)(f_s + m*416 + 8*j) = v;
      }
    }
    // -- wait until all WGs of this dir published slot s (parallel flag poll, no RMW)
    if (w == 0 && s > 0){
      bool act = lane < NW_;
      for (int it=0; it<2000000; ++it){
        int f = act ? __hip_atomic_load(myflags + lane, __ATOMIC_RELAXED, __HIP_MEMORY_SCOPE_AGENT)
                    : 0x7fffffff;
        if (__all(f >= s)) break;
        __builtin_amdgcn_s_sleep(1);
      }
    }
    __syncthreads();
    // -- stage h(s): 4800 contiguous qwords, agent-scope loads, chunked layout
    {
      const ull_t* hsrc = (const ull_t*)(hhd + (size_t)(dir*257 + s)*SLOT_DW);
      ull_t v[10]; int di[10];
      #pragma unroll
      for (int i=0;i<10;++i){
        int idx = tid + 512*i;
        if (i < 9 || idx < 4800){
          int gc = idx / 192;
          int r  = idx - gc*192;
          int b  = r/3, q = r - b*3;
          di[i] = b*164 + gc*6 + 2*q;
          v[i] = __hip_atomic_load(hsrc + idx, __ATOMIC_RELAXED, __HIP_MEMORY_SCOPE_AGENT);
        }
      }
      #pragma unroll
      for (int i=0;i<10;++i){
        int idx = tid + 512*i;
        if (i < 9 || idx < 4800) *(ull_t*)(hdl + di[i]) = v[i];
      }
    }
    __syncthreads();
    // -- MFMA: gates(64 x 48-slice) = feat*Wih^T + h*Whh^T
    f32x4 acc0a = {0,0,0,0}, acc0b = {0,0,0,0}, acc1a = {0,0,0,0}, acc1b = {0,0,0,0};
    #pragma unroll
    for (int kk=0; kk<13; ++kk){
      bf16x8 a = *(const bf16x8*)(f_s + arow_f + 32*kk);
      if (kk & 1){
        acc0b = __builtin_amdgcn_mfma_f32_16x16x32_bf16(a, B2[0][kk], acc0b, 0,0,0);
        if (two) acc1b = __builtin_amdgcn_mfma_f32_16x16x32_bf16(a, B2[1][kk], acc1b, 0,0,0);
      } else {
        acc0a = __builtin_amdgcn_mfma_f32_16x16x32_bf16(a, B2[0][kk], acc0a, 0,0,0);
        if (two) acc1a = __builtin_amdgcn_mfma_f32_16x16x32_bf16(a, B2[1][kk], acc1a, 0,0,0);
      }
    }
    #pragma unroll
    for (int kk=0; kk<10; ++kk){
      bf16x8 a = *(const bf16x8*)(h_s + arow_h + 32*kk);
      if (kk & 1){
        acc0b = __builtin_amdgcn_mfma_f32_16x16x32_bf16(a, B1[0][kk], acc0b, 0,0,0);
        if (two) acc1b = __builtin_amdgcn_mfma_f32_16x16x32_bf16(a, B1[1][kk], acc1b, 0,0,0);
      } else {
        acc0a = __builtin_amdgcn_mfma_f32_16x16x32_bf16(a, B1[0][kk], acc0a, 0,0,0);
        if (two) acc1a = __builtin_amdgcn_mfma_f32_16x16x32_bf16(a, B1[1][kk], acc1a, 0,0,0);
      }
    }
    // -- write gate fragments to g_s
    {
      int nb = 16*tnb + (lane & 15);
      int mr = 16*tm + 4*(lane >> 4);
      f32x4 s0 = acc0a + acc0b;
      #pragma unroll
      for (int r4=0; r4<4; ++r4) g_s[(mr+r4)*52 + nb] = s0[r4];
      if (two){
        f32x4 s1 = acc1a + acc1b;
        #pragma unroll
        for (int r4=0; r4<4; ++r4) g_s[(mr+r4)*52 + nb + 16] = s1[r4];
      }
    }
    __syncthreads();
    // -- elementwise LSTM update + publish carried h (own contiguous chunk)
    if (tid < 384){
      int mt = (mask_s[m_u*8 + (t>>5)] >> (t&31)) & 1u;
      float4 ga = *(const float4*)(g_s + m_u*52 + 8*up);
      float4 gb = *(const float4*)(g_s + m_u*52 + 8*up + 4);
      {
        float gi = sigm (ga.x + bias_a.x);
        float gf = sigm (ga.y + bias_a.y);
        float gg = ftanh(ga.z + bias_a.z);
        float go = sigm (ga.w + bias_a.w);
        float cn = gf*c_a + gi*gg;
        float hn = go*ftanh(cn);
        if (mt){ c_a = cn; h_a = hn; }
      }
      {
        float gi = sigm (gb.x + bias_b.x);
        float gf = sigm (gb.y + bias_b.y);
        float gg = ftanh(gb.z + bias_b.z);
        float go = sigm (gb.w + bias_b.w);
        float cn = gf*c_b + gi*gg;
        float hn = go*ftanh(cn);
        if (mt){ c_b = cn; h_b = hn; }
      }
      unsigned pack = (unsigned)f2bf(h_a) | ((unsigned)f2bf(h_b) << 16);
      unsigned* hdst = hhd + (size_t)(dir*257 + s + 1)*SLOT_DW + (g*64 + m_u)*6 + up;
      __hip_atomic_store(hdst, pack, __ATOMIC_RELAXED, __HIP_MEMORY_SCOPE_AGENT);
    }
    asm volatile("s_waitcnt vmcnt(0)" ::: "memory");
    __syncthreads();   // all waves' stores drained
    if (tid == 0)
      __hip_atomic_store(myflags + g, s + 1, __ATOMIC_RELAXED, __HIP_MEMORY_SCOPE_AGENT);
  }
}

// ---------- 5. logits (fused both dirs + out_b): lg[seq][tag] = h_f.oW_f + h_b.oW_b + out_b
__global__ __launch_bounds__(320) void k_logits(const unsigned int* __restrict__ hhd,
    const float* __restrict__ outW, const float* __restrict__ outb, float* __restrict__ lg){
  extern __shared__ char lsm[];
  float*    w_l = (float*)lsm;                    // [20][608] f32 = 48,640 B
  ushort_t* h_l = (ushort_t*)(lsm + 20*608*4);    // [16][608] bf16 = 19,456 B
  int tid = threadIdx.x;
  for (int idx=tid; idx<20*608; idx+=320){
    int tag = idx/608, k = idx - tag*608;
    w_l[idx] = (k < 600) ? outW[(size_t)tag*600 + k] : 0.f;
  }
  unsigned* hld = (unsigned*)h_l;
  int seq0 = blockIdx.x*16;
  for (int idx=tid; idx<16*304; idx+=320){        // 304 dwords/row (last 4 zeroed)
    int m = idx/304, d = idx - m*304;
    unsigned v = 0u;
    if (d < 300){
      int dir = d >= 150;
      int dd = d - dir*150;
      int gc = dd/6, q = dd - gc*6;
      int seq = seq0 + m;
      int b = seq >> 8, t = seq & 255;
      int slot = dir ? (T_ - t) : (t + 1);
      v = hhd[(size_t)(dir*257 + slot)*SLOT_DW + (gc*64 + b)*6 + q];
    }
    hld[m*304 + d] = v;
  }
  __syncthreads();
  int sq = tid/20, tag = tid - sq*20;
  const ushort_t* hr = h_l + sq*608;
  const float*    wr = w_l + tag*608;
  float acc = 0.f;
  #pragma unroll
  for (int jj=0; jj<152; ++jj){
    ushort4 h4 = *(const ushort4*)(hr + 4*jj);
    float4  wv = *(const float4*)(wr + 4*jj);
    acc += bf2f(h4.x)*wv.x + bf2f(h4.y)*wv.y + bf2f(h4.z)*wv.z + bf2f(h4.w)*wv.w;
  }
  lg[(size_t)(seq0+sq)*NTAG + tag] = acc + outb[tag];
}

// ---------- 6. CRF forward + gold score: register-resident, shfl alpha, no LDS/barriers
__global__ __launch_bounds__(64) void k_crf(const float* __restrict__ lg,
    const float* __restrict__ tr, const int* __restrict__ word_x,
    const int* __restrict__ y, float* __restrict__ out){
  int b = blockIdx.x, lane = threadIdx.x;
  float trr[20];
  if (lane < NTAG){
    #pragma unroll
    for (int j=0;j<NTAG;++j) trr[j] = tr[lane*NTAG + j];
  }
  float tstop = (lane < NTAG) ? tr[STOP_*NTAG + lane] : NEG_;
  unsigned mbits = 0u;
  if (lane < 8){
    const int* wp = word_x + b*T_ + lane*32;
    #pragma unroll
    for (int j4=0; j4<8; ++j4){
      int4 v = *(const int4*)(wp + 4*j4);
      mbits |= (v.x>0 ? 1u:0u) << (4*j4);
      mbits |= (v.y>0 ? 1u:0u) << (4*j4+1);
      mbits |= (v.z>0 ? 1u:0u) << (4*j4+2);
      mbits |= (v.w>0 ? 1u:0u) << (4*j4+3);
    }
  }
  const float* lgb = lg + (size_t)b*T_*NTAG;
  float alpha = (lane == START_) ? 0.f : NEG_;
  float hv_cur = lgb[lane];                 // t=0 slice (lanes>=20 read in-bounds junk)
  #pragma unroll 1
  for (int t=0; t<T_; ++t){
    float hv_next = (t < T_-1) ? lgb[(size_t)(t+1)*NTAG + lane] : 0.f;   // prefetch
    unsigned mrow = __shfl(mbits, t >> 5);
    int mt = (mrow >> (t & 31)) & 1;
    float aj[20];
    #pragma unroll
    for (int j=0;j<NTAG;++j) aj[j] = __shfl(alpha, j) + trr[j];
    float mx = -3.4e38f;
    #pragma unroll
    for (int j=0;j<NTAG;++j) mx = fmaxf(mx, aj[j]);
    float ss = 0.f;
    #pragma unroll
    for (int j=0;j<NTAG;++j) ss += __expf(aj[j] - mx);
    float anew = __logf(ss) + mx + hv_cur;
    if (mt && lane < NTAG) alpha = anew;
    hv_cur = hv_next;
  }
  // Z = lse(alpha + tr[STOP])
  float val = alpha + tstop;
  float mx = -3.4e38f;
  #pragma unroll
  for (int j=0;j<NTAG;++j) mx = fmaxf(mx, __shfl(val, j));
  float ss = 0.f;
  #pragma unroll
  for (int j=0;j<NTAG;++j) ss += __expf(__shfl(val, j) - mx);
  float Z = __logf(ss) + mx;
  // gold score (lg already includes out_b and both dirs)
  float sc = 0.f; int cnt = 0;
  #pragma unroll 1
  for (int q=0;q<4;++q){
    int t = lane + 64*q;
    if (word_x[b*T_ + t] > 0){
      int yt = y[b*T_ + t];
      int yp = (t == 0) ? START_ : y[b*T_ + t - 1];
      sc += lgb[(size_t)t*NTAG + yt] + tr[yt*NTAG + yp];
      cnt++;
    }
  }
  for (int off=32; off; off>>=1){
    sc += __shfl_down(sc, off);
    cnt += __shfl_down(cnt, off);
  }
  if (lane == 0){
    int last = y[b*T_ + cnt - 1];
    sc += tr[STOP_*NTAG + last];
    out[b] = Z - sc;
  }
}

extern "C" void kernel_launch(void* const* d_in, const int* in_sizes, int n_in,
                              void* d_out, int out_size, void* d_ws, size_t ws_size,
                              hipStream_t stream) {
  (void)in_sizes; (void)n_in; (void)out_size; (void)ws_size;
  const int*   word_x  = (const int*)  d_in[0];
  const int*   char_x  = (const int*)  d_in[1];
  const int*   y       = (const int*)  d_in[2];
  const float* wemb    = (const float*)d_in[3];
  const float* cemb    = (const float*)d_in[4];
  const float* cWih    = (const float*)d_in[5];
  const float* cWhh    = (const float*)d_in[6];
  const float* cbih    = (const float*)d_in[7];
  const float* cbhh    = (const float*)d_in[8];
  const float* fWih    = (const float*)d_in[9];
  const float* fWhh    = (const float*)d_in[10];
  const float* fbih    = (const float*)d_in[11];
  const float* fbhh    = (const float*)d_in[12];
  const float* bWih    = (const float*)d_in[13];
  const float* bWhh    = (const float*)d_in[14];
  const float* bbih    = (const float*)d_in[15];
  const float* bbhh    = (const float*)d_in[16];
  const float* outW    = (const float*)d_in[17];
  const float* outb    = (const float*)d_in[18];
  const float* trans   = (const float*)d_in[19];
  float* out = (float*)d_out;

  char* ws = (char*)d_ws;
  // layout (bytes, 256-aligned):
  float*        Ec_t   = (float*)       (ws + 0);          //   204,800
  float*        c_h    = (float*)       (ws + 204800);     // 6,553,600
  ushort_t*     feat   = (ushort_t*)    (ws + 6758400);    // 13,107,200
  unsigned int* hh     = (unsigned int*)(ws + 19865600);   // 19,737,600
  int*          flags  = (int*)         (ws + 39603200);   // 64 ints = 256
  float*        lg     = (float*)       (ws + 39603456);   // 16384*20*4 + pad = 1,311,232

  static const int LDS_W = 64*328*2 + 64*416*2 + 64*52*4 + 64*8*4;   // 110,592 B
  static const int LDS_C = 64*132*2 + 64*401*4;                      // 119,552 B
  static const int LDS_L = 20*608*4 + 16*608*2;                      //  68,096 B
  hipFuncSetAttribute((const void*)k_word2, hipFuncAttributeMaxDynamicSharedMemorySize, LDS_W);
  hipFuncSetAttribute((const void*)k_char,  hipFuncAttributeMaxDynamicSharedMemorySize, LDS_C);
  hipFuncSetAttribute((const void*)k_logits,hipFuncAttributeMaxDynamicSharedMemorySize, LDS_L);

  hipLaunchKernelGGL(k_prep, dim3(276), dim3(256), 0, stream, hh, flags, cemb, cWih, cbih, cbhh, Ec_t);
  hipLaunchKernelGGL(k_char, dim3(256), dim3(256), LDS_C, stream, Ec_t, cWhh, char_x, c_h);
  hipLaunchKernelGGL(k_feat, dim3(6400), dim3(256), 0, stream, word_x, wemb, c_h, feat);
  hipLaunchKernelGGL(k_word2, dim3(2*NW_), dim3(512), LDS_W, stream,
                     feat, hh, fWih, fWhh, fbih, fbhh, bWih, bWhh, bbih, bbhh, word_x, flags);
  hipLaunchKernelGGL(k_logits, dim3(NSEQ/16), dim3(320), LDS_L, stream, hh, outW, outb, lg);
  hipLaunchKernelGGL(k_crf, dim3(64), dim3(64), 0, stream, lg, trans, word_x, y, out);
}